// Round 12
// baseline (114.003 us; speedup 1.0000x reference)
//
#include <hip/hip_runtime.h>
#include <math.h>

#pragma clang fp contract(off)

// Problem constants
#define B_   128
#define CI_  16
#define CO_  32
#define H_   32
#define W_   32
#define HO_  30
#define WO_  30
#define P_   900                 // HO*WO
#define CP_  (CO_*P_)            // 28800
#define N_   ((size_t)B_*CP_)    // 3686400 elements per tensor
#define NBLK_CONV (4*30*8)       // stat slots = 960 (UNCHANGED -> stats bitwise identical)
#define WSTRIDE_O 129600         // CI_*P_*9
#define WSTRIDE_C 8100           // P_*9
#define FFC_ (H_*W_)             // 1024  (channel stride in ff)
#define FFB_ (CI_*H_*W_)         // 16384 (batch stride in ff)
#define FFTOT_ (B_*FFB_)         // 2097152 total ff floats

// d_out layout (4*N_ floats): [0,N)=soma, [N,2N)=spike, [2N,3N)=a_new, [3N,4N)=b_new.
// Slot [3N,4N) temporarily holds the f32 conv value; LIF reads it before
// overwriting with b_new.

// async global->LDS. LDS dest is wave-uniform base + lane*width.
typedef __attribute__((address_space(1))) const unsigned int gas_uint;
typedef __attribute__((address_space(3))) unsigned int las_uint;
__device__ __forceinline__ void gload_lds4(const float* g, float* l) {
    __builtin_amdgcn_global_load_lds((gas_uint*)g, (las_uint*)l, 4, 0, 0);
}
__device__ __forceinline__ void gload_lds16(const float* g, float* l) {
    __builtin_amdgcn_global_load_lds((gas_uint*)g, (las_uint*)l, 16, 0, 0);
}

// ---------------------------------------------------------------------------
// Kernel 1: locally-connected conv. R11 VERBATIM (current champion component:
// ~71-75 us, VGPR 80, occ 26%, conflicts 1.35e6). O-split per the R10 lesson
// (per-block cost dominated by per-o weight staging): block = 16 o x 8 w x
// 16 b, grid dim3(8,30,8) = 1920 (~7.5/CU). Weight-sharing blocks 240 apart
// = 0 mod 8 -> same XCD L2. Thread = 1o x 2w x 4b. Stats: same 960x32 f64
// slots, same lane sums, same shuffle tree -> bitwise identical outputs.
// NOTE (R4/R6 lessons): no __launch_bounds__ VGPR cap, no pointer rotation,
// no >2-deep pipeline.
// ---------------------------------------------------------------------------
__global__ __launch_bounds__(256) void conv_kernel(
    const float* __restrict__ ff, const float* __restrict__ weight,
    const float* __restrict__ conv_bias, float* __restrict__ outf,
    double* __restrict__ part_sum, double* __restrict__ part_sumsq)
{
#pragma clang fp contract(off)
    const int tid = threadIdx.x;
    const int og  = (tid & 3) | ((tid >> 6) << 2);   // 0..15 (4 per wave)
    const int wg2 = (tid >> 2) & 3;                  // 0..3
    const int bg  = (tid >> 4) & 3;                  // 0..3
    const int wave = tid >> 6;
    const int wt = blockIdx.x & 3;      // 0..3
    const int os = blockIdx.x >> 2;     // 0..1  (o half: os*16 .. os*16+15)
    const int h  = blockIdx.y;          // 0..29
    const int b0 = blockIdx.z * 16;     // 16 batches per block
    const int w0 = wt * 8 + wg2 * 2;
    const bool val = !(wt == 3 && wg2 == 3);
    const int wwave = tid & ~63;        // wave-uniform lane-0 tid

    __shared__ float wgl[2][1216];      // [buf][ol*68 + w*8 + k] + k8 plane at 1088
    __shared__ float ffs[2][576];       // [buf][bb*36 + r*12 + cc]

    // ---- c-independent staging offsets (all in-bounds by construction) ----
    int wq_off[4];
#pragma unroll
    for (int q = 0; q < 4; ++q) {
        int s = q * 256 + tid;          // 0..1023
        int ol = s >> 6, w = (s >> 3) & 7, k = s & 7;
        int colc = wt * 8 + w; if (colc > 29) colc = 29;   // edge clamp (garbage -> invalid threads only)
        wq_off[q] = (os * 16 + ol) * WSTRIDE_O + (h * WO_ + colc) * 9 + k;
    }
    int w8_off = 0;
    const bool k8on = (tid < 128);      // waves 0,1 stage the k=8 plane (128 floats)
    if (k8on) {
        int ol = tid >> 3, w = tid & 7;
        int colc = wt * 8 + w; if (colc > 29) colc = 29;
        w8_off = (os * 16 + ol) * WSTRIDE_O + (h * WO_ + colc) * 9 + 8;
    }
    const bool fon = (tid < 144);       // 144 lanes x 16B = 576 floats
    int f_off = 0;
    if (fon) {
        int s0 = 4 * tid;               // 0,4,...,572
        int bb = s0 / 36, rm = s0 % 36, r = rm / 12, cc0 = rm % 12;
        f_off = (b0 + bb) * FFB_ + (h + r) * W_ + wt * 8 + cc0;   // 16B-aligned
    }

    float acc[2][4];                     // [ww][j]
#pragma unroll
    for (int ww = 0; ww < 2; ++ww)
#pragma unroll
        for (int j = 0; j < 4; ++j) acc[ww][j] = 0.f;

    auto stage = [&](int c, int buf) {
        const float* wsrc = weight + c * WSTRIDE_C;
#pragma unroll
        for (int q = 0; q < 4; ++q)
            gload_lds4(wsrc + wq_off[q], &wgl[buf][(q * 4 + wave) * 68]);
        if (k8on) gload_lds4(wsrc + w8_off, &wgl[buf][1088 + (wave << 6)]);
        if (fon) {
            int g = f_off + c * FFC_;
            if (g > FFTOT_ - 4) g = FFTOT_ - 4;   // corner clamp (garbage slots only)
            gload_lds16(ff + g, &ffs[buf][4 * wwave]);
        }
    };

    auto compute_c = [&](int buf) {
        float wk[2][9];
#pragma unroll
        for (int ww = 0; ww < 2; ++ww) {
            const int w = wg2 * 2 + ww;
            const float* wp = &wgl[buf][og * 68 + w * 8];     // 272B group stride, 16B-aligned
            const float4 a = *reinterpret_cast<const float4*>(wp);
            const float4 b = *reinterpret_cast<const float4*>(wp + 4);
            wk[ww][0] = a.x; wk[ww][1] = a.y; wk[ww][2] = a.z; wk[ww][3] = a.w;
            wk[ww][4] = b.x; wk[ww][5] = b.y; wk[ww][6] = b.z; wk[ww][7] = b.w;
            wk[ww][8] = wgl[buf][1088 + og * 8 + w];
        }
#pragma unroll
        for (int j = 0; j < 4; ++j) {
            const int bb = bg * 4 + j;
            float fr[3][4];
#pragma unroll
            for (int r = 0; r < 3; ++r) {
                const float2 u = *reinterpret_cast<const float2*>(&ffs[buf][bb * 36 + r * 12 + wg2 * 2]);
                const float2 v = *reinterpret_cast<const float2*>(&ffs[buf][bb * 36 + r * 12 + wg2 * 2 + 2]);
                fr[r][0] = u.x; fr[r][1] = u.y; fr[r][2] = v.x; fr[r][3] = v.y;
            }
#pragma unroll
            for (int ww = 0; ww < 2; ++ww) {
                float a = acc[ww][j];
#pragma unroll
                for (int kh = 0; kh < 3; ++kh)
#pragma unroll
                    for (int kw = 0; kw < 3; ++kw) {
                        float prod = wk[ww][kh * 3 + kw] * fr[kh][ww + kw];
                        a = a + prod;      // no FMA, (c,kh,kw) order
                    }
                acc[ww][j] = a;
            }
        }
    };

    stage(0, 0);
    __syncthreads();
    for (int cs = 0; cs < CI_; cs += 2) {
        if (cs + 1 < CI_) stage(cs + 1, 1);   // prefetch overlaps compute
        compute_c(0);
        __syncthreads();
        if (cs + 2 < CI_) stage(cs + 2, 0);
        compute_c(1);
        __syncthreads();
    }

    // epilogue: bias, park conv values, exact f64 per-slot per-channel stats
    double s1 = 0.0, s2 = 0.0;
    const int o = os * 16 + og;
    if (val) {
        const int pidx = o * P_ + h * WO_ + w0;
        const float2 bi = *reinterpret_cast<const float2*>(conv_bias + pidx);
#pragma unroll
        for (int j = 0; j < 4; ++j) {
            const int b = b0 + bg * 4 + j;
            const size_t n = (size_t)b * CP_ + (size_t)pidx;
            float v0 = acc[0][j] + bi.x;         // f32, same as ref
            float v1 = acc[1][j] + bi.y;
            *reinterpret_cast<float2*>(outf + 3 * N_ + n) = make_float2(v0, v1);
            double d0 = (double)v0, d1 = (double)v1;
            s1 += d0; s2 += d0 * d0;
            s1 += d1; s2 += d1 * d1;
        }
    }
    // deterministic reduce over the 16 lanes (stride 4) sharing og
#pragma unroll
    for (int d = 4; d < 64; d <<= 1) {
        s1 += __shfl_xor(s1, d);
        s2 += __shfl_xor(s2, d);
    }
    if ((tid & 60) == 0) {               // wg2==0 && bg==0
        int blk = (blockIdx.z * 30 + blockIdx.y) * 4 + wt;   // 0..959 (same slots)
        part_sum  [blk * CO_ + o] = s1;
        part_sumsq[blk * CO_ + o] = s2;
    }
}

// ---------------------------------------------------------------------------
// Kernel 2: BN finalize — deterministic f64 reduction of partials (960
// slots), then f32 mean / inv_std per channel. UNCHANGED.
// ---------------------------------------------------------------------------
__global__ __launch_bounds__(256) void bn_finalize(
    const double* __restrict__ part_sum, const double* __restrict__ part_sumsq,
    float* __restrict__ Mb)
{
#pragma clang fp contract(off)
    const int o = blockIdx.x;
    const int tid = threadIdx.x;
    double s1 = 0.0, s2 = 0.0;
    for (int i = tid; i < NBLK_CONV; i += 256) {
        s1 += part_sum[i * CO_ + o];
        s2 += part_sumsq[i * CO_ + o];
    }
    __shared__ double r1[256], r2[256];
    r1[tid] = s1; r2[tid] = s2;
    __syncthreads();
    for (int s = 128; s > 0; s >>= 1) {
        if (tid < s) { r1[tid] += r1[tid + s]; r2[tid] += r2[tid + s]; }
        __syncthreads();
    }
    if (tid == 0) {
        const double cnt = (double)(B_ * (size_t)P_);
        double mean = r1[0] / cnt;
        float meanf = (float)mean;
        double md = (double)meanf;
        double var = r2[0] / cnt - 2.0 * md * (r1[0] / cnt) + md * md;
        float varf = (float)var;
        float invf = 1.0f / sqrtf(varf + 1e-5f);
        Mb[o]       = meanf;
        Mb[CO_ + o] = invf;
    }
}

// ---------------------------------------------------------------------------
// Kernel 3: fused recurrent-bmm + LIF. R7 geometry/math VERBATIM with the
// barrier structure fixed: ALL 8 spike tiles staged up-front via
// global_load_lds (no VGPR roundtrip: dest = wave-uniform base + lane*4;
// wave w's 64 lanes cover rows i=2w,2w+1 x 32 p -> lane-linear), then ONE
// __syncthreads(), then 8 iterations with register prefetch and NO barriers
// -- the 16 waves run independently (R7 had 8 lgkmcnt-barrier convoys at
// 1.8 blocks/CU; that was the 70us). Own spike read back from LDS (staged
// value, bit-identical). LDS 32KB -> still 2 blocks/CU.
// Per-output arithmetic identical (j-ascending mul-then-add, same formulas)
// => bit-identical outputs.
// ---------------------------------------------------------------------------
__global__ __launch_bounds__(1024) void lif_rec_kernel(
    float* __restrict__ outf, const float* __restrict__ local_rec,
    const float* __restrict__ tau_m, const float* __restrict__ tau_adp,
    const float* __restrict__ tau_a, const float* __restrict__ Mb,
    const float* __restrict__ gamma, const float* __restrict__ beta,
    const float* __restrict__ fb, const float* __restrict__ soma_t,
    const float* __restrict__ spk_t, const float* __restrict__ a_curr,
    const float* __restrict__ b_t)
{
#pragma clang fp contract(off)
    const int D    = blockIdx.x;
    const int pt8  = D & 7;
    const int rest = D >> 3;
    const int by   = rest & 15;
    const int ptq  = rest >> 4;          // 0..3
    const int pt   = ptq * 8 + pt8;      // 0..31
    if (pt >= 29) return;                // 29 p-tiles cover P_=900

    const int tid = threadIdx.x;
    const int pp  = tid & 31;
    const int i   = tid >> 5;            // channel 0..31
    const int p   = pt * 32 + pp;
    const bool pv = (p < P_);
    const int pcl = pv ? p : (P_ - 1);   // clamped (garbage -> !pv columns only)
    const int b0  = by * 8;
    const int wave = tid >> 6;           // 0..15; wave covers i = 2*wave, 2*wave+1

    __shared__ float sp[8][CO_][32];     // 32 KB: all 8 batch spike tiles

    // ---- stage ALL 8 spike tiles via global_load_lds (zero VGPR cost) ----
    // global src per lane: spk[b0+bb, i, pcl]; LDS dest wave-uniform
    // &sp[bb][2*wave][0] + lane*4 covers rows 2w,2w+1 lane-linearly.
    {
        const float* gsrc = spk_t + (size_t)b0 * CP_ + (size_t)i * P_ + pcl;
#pragma unroll
        for (int bb = 0; bb < 8; ++bb)
            gload_lds4(gsrc + (size_t)bb * CP_, &sp[bb][wave * 2][0]);
    }

    // per-thread invariants
    float L[32];
    float meanf = 0.f, invf = 0.f, gm = 0.f, be = 0.f;
    float al = 0.f, rh = 0.f, et = 0.f;
    int rem = 0;
    if (pv) {
        const float4* lp = reinterpret_cast<const float4*>(local_rec + (size_t)p * (CO_ * CO_) + i * CO_);
#pragma unroll
        for (int q = 0; q < 8; ++q) {
            float4 v = lp[q];
            L[4 * q] = v.x; L[4 * q + 1] = v.y; L[4 * q + 2] = v.z; L[4 * q + 3] = v.w;
        }
        rem = i * P_ + p;
        meanf = Mb[i]; invf = Mb[CO_ + i];
        gm = gamma[i]; be = beta[i];
        // identical f32 ops to the original tau table: f32 divide then f32 exp
        al = expf(-0.5f / tau_m[rem]);
        rh = expf(-0.5f / tau_adp[rem]);
        et = expf(-0.5f / tau_a[rem]);
    }

    // prologue: iteration-0 operands into registers
    size_t n = (size_t)b0 * CP_ + (size_t)rem;
    float cv_c = 0.f, bt_c = 0.f, ac_c = 0.f, fb_c = 0.f, so_c = 0.f;
    if (pv) {
        cv_c = outf[3 * N_ + n]; bt_c = b_t[n];
        ac_c = a_curr[n]; fb_c = fb[n]; so_c = soma_t[n];
    }

    __syncthreads();                     // ONE barrier: all spike tiles landed

#pragma unroll
    for (int bb = 0; bb < 8; ++bb) {
        // prefetch next iteration's operands (no barriers ahead -> compiler
        // keeps them in flight under this iteration's compute)
        float cv_n = 0.f, bt_n = 0.f, ac_n = 0.f, fb_n = 0.f, so_n = 0.f;
        if (bb + 1 < 8 && pv) {
            const size_t nn = n + (size_t)CP_;
            cv_n = outf[3 * N_ + nn]; bt_n = b_t[nn];
            ac_n = a_curr[nn]; fb_n = fb[nn]; so_n = soma_t[nn];
        }
        if (pv) {
            // rec: sequential f32 dot over j, no FMA (np einsum order)
            float rec = 0.f;
#pragma unroll
            for (int j = 0; j < CO_; ++j) {
                float prod = L[j] * sp[bb][j][pp];
                rec = rec + prod;
            }
            const float sk = sp[bb][i][pp];      // own staged spike (bit-identical)

            // BN exactly as reference
            float t  = cv_c - meanf;
            float x  = t * invf;
            float xg = x * gm;
            float cx = xg + be;
            cx = cx + rec;

            // b_new = rho*b_t + (1-rho)*spk
            float rb  = rh * bt_c;
            float omr = 1.0f - rh;
            float os  = omr * sk;
            float bn  = rb + os;
            // new_thre = 0.1 + 1.8*b_new
            float tb = 1.8f * bn;
            float th = 0.1f + tb;
            // a_new = eta*a_curr + fb
            float ea = et * ac_c;
            float an = ea + fb_c;
            // sigmoid
            float sg = 1.0f / (1.0f + expf(-an));
            // soma_new = alpha*soma + (sig-0.5) + cx - thre*spk  (left-to-right)
            float as = al * so_c;
            float s5 = sg - 0.5f;
            float u1 = as + s5;
            float u2 = u1 + cx;
            float ts = th * sk;
            float sn = u2 - ts;

            outf[n]          = sn;
            outf[N_ + n]     = ((sn - th) > 0.0f) ? 1.f : 0.f;
            outf[2 * N_ + n] = an;
            outf[3 * N_ + n] = bn;                                // overwrites conv
        }
        cv_c = cv_n; bt_c = bt_n; ac_c = ac_n; fb_c = fb_n; so_c = so_n;
        n += (size_t)CP_;
    }
}

extern "C" void kernel_launch(void* const* d_in, const int* in_sizes, int n_in,
                              void* d_out, int out_size, void* d_ws, size_t ws_size,
                              hipStream_t stream)
{
    const float* ff        = (const float*)d_in[0];
    const float* fb        = (const float*)d_in[1];
    const float* soma_t    = (const float*)d_in[2];
    const float* spk_t     = (const float*)d_in[3];
    const float* a_curr    = (const float*)d_in[4];
    const float* b_t       = (const float*)d_in[5];
    const float* weight    = (const float*)d_in[6];
    const float* conv_bias = (const float*)d_in[7];
    const float* local_rec = (const float*)d_in[8];
    const float* gamma     = (const float*)d_in[9];
    const float* beta      = (const float*)d_in[10];
    const float* tau_m     = (const float*)d_in[11];
    const float* tau_adp   = (const float*)d_in[12];
    const float* tau_a     = (const float*)d_in[13];

    // ws: f64 partials then Mb (~0.5 MB total)
    double* part_sum = (double*)d_ws;                       // NBLK_CONV*CO_
    double* part_sq  = part_sum + (size_t)NBLK_CONV * CO_;  // NBLK_CONV*CO_
    float*  Mb       = (float*)(part_sq + (size_t)NBLK_CONV * CO_);  // 64

    float* outf = (float*)d_out;

    conv_kernel<<<dim3(8, 30, 8), 256, 0, stream>>>(
        ff, weight, conv_bias, outf, part_sum, part_sq);
    bn_finalize<<<dim3(CO_), 256, 0, stream>>>(part_sum, part_sq, Mb);
    lif_rec_kernel<<<dim3(512), 1024, 0, stream>>>(
        outf, local_rec, tau_m, tau_adp, tau_a, Mb, gamma, beta,
        fb, soma_t, spk_t, a_curr, b_t);
}

// Round 13
// 108.348 us; speedup vs baseline: 1.0522x; 1.0522x over previous
//
#include <hip/hip_runtime.h>
#include <math.h>

#pragma clang fp contract(off)

// Problem constants
#define B_   128
#define CI_  16
#define CO_  32
#define H_   32
#define W_   32
#define HO_  30
#define WO_  30
#define P_   900                 // HO*WO
#define CP_  (CO_*P_)            // 28800
#define N_   ((size_t)B_*CP_)    // 3686400 elements per tensor
#define NBLK_CONV (4*30*8)       // stat slots = 960 (UNCHANGED -> stats bitwise identical)
#define WSTRIDE_O 129600         // CI_*P_*9
#define WSTRIDE_C 8100           // P_*9
#define FFC_ (H_*W_)             // 1024  (channel stride in ff)
#define FFB_ (CI_*H_*W_)         // 16384 (batch stride in ff)
#define FFTOT_ (B_*FFB_)         // 2097152 total ff floats

// d_out layout (4*N_ floats): [0,N)=soma, [N,2N)=spike, [2N,3N)=a_new, [3N,4N)=b_new.
// Slot [3N,4N) temporarily holds the f32 conv value; LIF reads it before
// overwriting with b_new.

// async global->LDS. LDS dest is wave-uniform base + lane*width.
typedef __attribute__((address_space(1))) const unsigned int gas_uint;
typedef __attribute__((address_space(3))) unsigned int las_uint;
__device__ __forceinline__ void gload_lds4(const float* g, float* l) {
    __builtin_amdgcn_global_load_lds((gas_uint*)g, (las_uint*)l, 4, 0, 0);
}
__device__ __forceinline__ void gload_lds16(const float* g, float* l) {
    __builtin_amdgcn_global_load_lds((gas_uint*)g, (las_uint*)l, 16, 0, 0);
}

// ---------------------------------------------------------------------------
// Kernel 1: locally-connected conv. LDS-BYTE-THROUGHPUT analysis (R12):
// DS bytes/output/channel: R11 tiling (1o x 2w x 4b) = 33 B; R5 tiling
// (2o x 2w x 4b) = 21 B. R5's real problems were grid density (960 blocks
// = 3.75/CU) and the wk bank conflict -- NOT the tiling. This kernel:
//  - thread = 2o x 2w x 4b (the 21 B/out tiling), 128-thread blocks
//    (2 waves), block = 16o x 8w x 16b, grid dim3(8,30,8) = 1920 (~7.5/CU).
//  - weight groups padded to 76 floats (304 B, a 16B multiple): lane bank =
//    (24*og + 16*wg2) mod 32 -> every bank pair hit exactly 2x -> 2-way =
//    free (m136) for the wk ds_read_b128.
//  - staging lane-linear: weight dword s = q*128+tid -> group ol = 2q+wave;
//    k8 plane 1 dword/thread; ff 576 dwords = width16 all threads + 16-lane
//    tail chunk.
//  - weight-sharing blocks (same bx,y; 8 z's) are 240 apart = 0 mod 8
//    -> same XCD L2 (R6-proven).
// Stats: SAME 960x32 f64 slots (os-halves write disjoint o's of shared
// slots), same per-lane sum order (per o: j-major, ww minor), same d=4..32
// shuffle tree -> slot values BITWISE identical -> outputs bit-identical.
// Per-output accumulation order (c outer, kh, kw; mul then add, no FMA).
// NOTE (R4/R6 lessons): no __launch_bounds__ VGPR cap, no pointer rotation,
// no >2-deep pipeline.
// ---------------------------------------------------------------------------
__global__ __launch_bounds__(128) void conv_kernel(
    const float* __restrict__ ff, const float* __restrict__ weight,
    const float* __restrict__ conv_bias, float* __restrict__ outf,
    double* __restrict__ part_sum, double* __restrict__ part_sumsq)
{
#pragma clang fp contract(off)
    const int tid = threadIdx.x;                     // 0..127
    const int og  = (tid & 3) | ((tid >> 6) << 2);   // 0..7 (o-pair index)
    const int wg2 = (tid >> 2) & 3;                  // 0..3
    const int bg  = (tid >> 4) & 3;                  // 0..3
    const int wave = tid >> 6;                       // 0..1
    const int wt = blockIdx.x & 3;      // 0..3
    const int os = blockIdx.x >> 2;     // 0..1  (o half: os*16 .. os*16+15)
    const int h  = blockIdx.y;          // 0..29
    const int b0 = blockIdx.z * 16;     // 16 batches per block
    const int w0 = wt * 8 + wg2 * 2;
    const bool val = !(wt == 3 && wg2 == 3);
    const int wwave = tid & ~63;        // wave-uniform lane-0 tid

    __shared__ float wgl[2][1344];      // 16 groups x 76 (64 data + 12 pad); k8 plane at 1216
    __shared__ float ffs[2][576];       // [buf][bb*36 + r*12 + cc]

    // ---- c-independent staging offsets (all in-bounds by construction) ----
    // weight dword s = q*128 + tid -> (ol = s>>6 in 0..15, w = (s>>3)&7, k = s&7)
    int wq_off[8];
#pragma unroll
    for (int q = 0; q < 8; ++q) {
        int s = q * 128 + tid;          // 0..1023
        int ol = s >> 6, w = (s >> 3) & 7, k = s & 7;
        int colc = wt * 8 + w; if (colc > 29) colc = 29;   // edge clamp (garbage -> invalid threads only)
        wq_off[q] = (os * 16 + ol) * WSTRIDE_O + (h * WO_ + colc) * 9 + k;
    }
    int w8_off;
    {
        int ol = tid >> 3, w = tid & 7;
        int colc = wt * 8 + w; if (colc > 29) colc = 29;
        w8_off = (os * 16 + ol) * WSTRIDE_O + (h * WO_ + colc) * 9 + 8;
    }
    // ff chunk 1: dwords 4*tid (slots 0..127); chunk 2: dwords 512+4*tid (tid<16)
    int f_off, f_off2 = 0;
    {
        int s0 = 4 * tid;
        int bb = s0 / 36, rm = s0 % 36, r = rm / 12, cc0 = rm % 12;
        f_off = (b0 + bb) * FFB_ + (h + r) * W_ + wt * 8 + cc0;   // 16B-aligned
    }
    const bool f2on = (tid < 16);
    if (f2on) {
        int s0 = 512 + 4 * tid;
        int bb = s0 / 36, rm = s0 % 36, r = rm / 12, cc0 = rm % 12;
        f_off2 = (b0 + bb) * FFB_ + (h + r) * W_ + wt * 8 + cc0;  // 16B-aligned
    }

    float acc[2][2][4];                  // [oo][ww][j]
#pragma unroll
    for (int oo = 0; oo < 2; ++oo)
#pragma unroll
        for (int ww = 0; ww < 2; ++ww)
#pragma unroll
            for (int j = 0; j < 4; ++j) acc[oo][ww][j] = 0.f;

    auto stage = [&](int c, int buf) {
        const float* wsrc = weight + c * WSTRIDE_C;
#pragma unroll
        for (int q = 0; q < 8; ++q)
            gload_lds4(wsrc + wq_off[q], &wgl[buf][(2 * q + wave) * 76]);
        gload_lds4(wsrc + w8_off, &wgl[buf][1216 + (wave << 6)]);
        {
            int g = f_off + c * FFC_;
            if (g > FFTOT_ - 4) g = FFTOT_ - 4;   // corner clamp (garbage slots only)
            gload_lds16(ff + g, &ffs[buf][4 * wwave]);
        }
        if (f2on) {
            int g = f_off2 + c * FFC_;
            if (g > FFTOT_ - 4) g = FFTOT_ - 4;
            gload_lds16(ff + g, &ffs[buf][512]);  // lanes 0..15 -> dwords 512..575
        }
    };

    auto compute_c = [&](int buf) {
        float wk[2][2][9];
#pragma unroll
        for (int oo = 0; oo < 2; ++oo)
#pragma unroll
            for (int ww = 0; ww < 2; ++ww) {
                const int ol = og * 2 + oo, w = wg2 * 2 + ww;
                const float* wp = &wgl[buf][ol * 76 + w * 8];     // 304B group stride, 16B-aligned
                const float4 a = *reinterpret_cast<const float4*>(wp);
                const float4 b = *reinterpret_cast<const float4*>(wp + 4);
                wk[oo][ww][0] = a.x; wk[oo][ww][1] = a.y; wk[oo][ww][2] = a.z; wk[oo][ww][3] = a.w;
                wk[oo][ww][4] = b.x; wk[oo][ww][5] = b.y; wk[oo][ww][6] = b.z; wk[oo][ww][7] = b.w;
                wk[oo][ww][8] = wgl[buf][1216 + ol * 8 + w];
            }
#pragma unroll
        for (int j = 0; j < 4; ++j) {
            const int bb = bg * 4 + j;
            float fr[3][4];
#pragma unroll
            for (int r = 0; r < 3; ++r) {
                const float2 u = *reinterpret_cast<const float2*>(&ffs[buf][bb * 36 + r * 12 + wg2 * 2]);
                const float2 v = *reinterpret_cast<const float2*>(&ffs[buf][bb * 36 + r * 12 + wg2 * 2 + 2]);
                fr[r][0] = u.x; fr[r][1] = u.y; fr[r][2] = v.x; fr[r][3] = v.y;
            }
#pragma unroll
            for (int oo = 0; oo < 2; ++oo)
#pragma unroll
                for (int ww = 0; ww < 2; ++ww) {
                    float a = acc[oo][ww][j];
#pragma unroll
                    for (int kh = 0; kh < 3; ++kh)
#pragma unroll
                        for (int kw = 0; kw < 3; ++kw) {
                            float prod = wk[oo][ww][kh * 3 + kw] * fr[kh][ww + kw];
                            a = a + prod;      // no FMA, (c,kh,kw) order
                        }
                    acc[oo][ww][j] = a;
                }
        }
    };

    stage(0, 0);
    __syncthreads();
    for (int cs = 0; cs < CI_; cs += 2) {
        if (cs + 1 < CI_) stage(cs + 1, 1);   // prefetch overlaps compute
        compute_c(0);
        __syncthreads();
        if (cs + 2 < CI_) stage(cs + 2, 0);
        compute_c(1);
        __syncthreads();
    }

    // epilogue: bias, park conv values, exact f64 per-slot per-channel stats
    double s1[2] = {0.0, 0.0}, s2[2] = {0.0, 0.0};
    const int o0 = os * 16 + og * 2;
    if (val) {
#pragma unroll
        for (int oo = 0; oo < 2; ++oo) {
            const int o = o0 + oo;
            const int pidx = o * P_ + h * WO_ + w0;
            const float2 bi = *reinterpret_cast<const float2*>(conv_bias + pidx);
#pragma unroll
            for (int j = 0; j < 4; ++j) {
                const int b = b0 + bg * 4 + j;
                const size_t n = (size_t)b * CP_ + (size_t)pidx;
                float v0 = acc[oo][0][j] + bi.x;     // f32, same as ref
                float v1 = acc[oo][1][j] + bi.y;
                *reinterpret_cast<float2*>(outf + 3 * N_ + n) = make_float2(v0, v1);
                double d0 = (double)v0, d1 = (double)v1;
                s1[oo] += d0; s2[oo] += d0 * d0;
                s1[oo] += d1; s2[oo] += d1 * d1;
            }
        }
    }
    // deterministic reduce over the 16 lanes (stride 4) sharing og
#pragma unroll
    for (int d = 4; d < 64; d <<= 1) {
#pragma unroll
        for (int oo = 0; oo < 2; ++oo) {
            s1[oo] += __shfl_xor(s1[oo], d);
            s2[oo] += __shfl_xor(s2[oo], d);
        }
    }
    if ((tid & 60) == 0) {               // wg2==0 && bg==0: tid in {0..3, 64..67}
        int blk = (blockIdx.z * 30 + blockIdx.y) * 4 + wt;   // 0..959 (same slots)
#pragma unroll
        for (int oo = 0; oo < 2; ++oo) {
            part_sum  [blk * CO_ + o0 + oo] = s1[oo];
            part_sumsq[blk * CO_ + o0 + oo] = s2[oo];
        }
    }
}

// ---------------------------------------------------------------------------
// Kernel 2: BN finalize — deterministic f64 reduction of partials (960
// slots), then f32 mean / inv_std per channel. UNCHANGED.
// ---------------------------------------------------------------------------
__global__ __launch_bounds__(256) void bn_finalize(
    const double* __restrict__ part_sum, const double* __restrict__ part_sumsq,
    float* __restrict__ Mb)
{
#pragma clang fp contract(off)
    const int o = blockIdx.x;
    const int tid = threadIdx.x;
    double s1 = 0.0, s2 = 0.0;
    for (int i = tid; i < NBLK_CONV; i += 256) {
        s1 += part_sum[i * CO_ + o];
        s2 += part_sumsq[i * CO_ + o];
    }
    __shared__ double r1[256], r2[256];
    r1[tid] = s1; r2[tid] = s2;
    __syncthreads();
    for (int s = 128; s > 0; s >>= 1) {
        if (tid < s) { r1[tid] += r1[tid + s]; r2[tid] += r2[tid + s]; }
        __syncthreads();
    }
    if (tid == 0) {
        const double cnt = (double)(B_ * (size_t)P_);
        double mean = r1[0] / cnt;
        float meanf = (float)mean;
        double md = (double)meanf;
        double var = r2[0] / cnt - 2.0 * md * (r1[0] / cnt) + md * md;
        float varf = (float)var;
        float invf = 1.0f / sqrtf(varf + 1e-5f);
        Mb[o]       = meanf;
        Mb[CO_ + o] = invf;
    }
}

// ---------------------------------------------------------------------------
// Kernel 3: fused recurrent-bmm + LIF. R7/R11 VERBATIM (component of the
// 110.7-us champion): LDS spike tile, parity double-buffer, register
// prefetch, lgkmcnt(0)-only barrier; 1024 thr = 32 i x 32 p; XCD-grouped
// 1D grid (512 blocks): pt determines D&7, so the 16 b-blocks sharing a
// local_rec/tau p-slice land on one XCD's L2.
// ---------------------------------------------------------------------------
__global__ __launch_bounds__(1024) void lif_rec_kernel(
    float* __restrict__ outf, const float* __restrict__ local_rec,
    const float* __restrict__ tau_m, const float* __restrict__ tau_adp,
    const float* __restrict__ tau_a, const float* __restrict__ Mb,
    const float* __restrict__ gamma, const float* __restrict__ beta,
    const float* __restrict__ fb, const float* __restrict__ soma_t,
    const float* __restrict__ spk_t, const float* __restrict__ a_curr,
    const float* __restrict__ b_t)
{
#pragma clang fp contract(off)
    const int D    = blockIdx.x;
    const int pt8  = D & 7;
    const int rest = D >> 3;
    const int by   = rest & 15;
    const int ptq  = rest >> 4;          // 0..3
    const int pt   = ptq * 8 + pt8;      // 0..31
    if (pt >= 29) return;                // 29 p-tiles cover P_=900

    const int tid = threadIdx.x;
    const int pp  = tid & 31;
    const int i   = tid >> 5;            // channel 0..31
    const int p   = pt * 32 + pp;
    const bool pv = (p < P_);
    const int b0  = by * 8;

    float L[32];
    float meanf = 0.f, invf = 0.f, gm = 0.f, be = 0.f;
    float al = 0.f, rh = 0.f, et = 0.f;
    int rem = 0;
    if (pv) {
        const float4* lp = reinterpret_cast<const float4*>(local_rec + (size_t)p * (CO_ * CO_) + i * CO_);
#pragma unroll
        for (int q = 0; q < 8; ++q) {
            float4 v = lp[q];
            L[4 * q] = v.x; L[4 * q + 1] = v.y; L[4 * q + 2] = v.z; L[4 * q + 3] = v.w;
        }
        rem = i * P_ + p;
        meanf = Mb[i]; invf = Mb[CO_ + i];
        gm = gamma[i]; be = beta[i];
        // identical f32 ops to the original tau table: f32 divide then f32 exp
        al = expf(-0.5f / tau_m[rem]);
        rh = expf(-0.5f / tau_adp[rem]);
        et = expf(-0.5f / tau_a[rem]);
    }

    __shared__ float sp[2][CO_][32];

    // prologue: iteration-0 operands into registers
    size_t n = (size_t)b0 * CP_ + (size_t)rem;
    float sk_c = 0.f, cv_c = 0.f, bt_c = 0.f, ac_c = 0.f, fb_c = 0.f, so_c = 0.f;
    if (pv) {
        sk_c = spk_t[n]; cv_c = outf[3 * N_ + n]; bt_c = b_t[n];
        ac_c = a_curr[n]; fb_c = fb[n]; so_c = soma_t[n];
    }

#pragma unroll
    for (int bb = 0; bb < 8; ++bb) {
        const int cb = bb & 1;
        if (pv) sp[cb][i][pp] = sk_c;
        // prefetch next iteration BEFORE the barrier (stays in flight: the
        // raw barrier below drains lgkmcnt only, not vmcnt)
        float sk_n = 0.f, cv_n = 0.f, bt_n = 0.f, ac_n = 0.f, fb_n = 0.f, so_n = 0.f;
        if (bb + 1 < 8 && pv) {
            const size_t nn = n + (size_t)CP_;
            sk_n = spk_t[nn]; cv_n = outf[3 * N_ + nn]; bt_n = b_t[nn];
            ac_n = a_curr[nn]; fb_n = fb[nn]; so_n = soma_t[nn];
        }
        asm volatile("s_waitcnt lgkmcnt(0)\n\ts_barrier" ::: "memory");
        if (pv) {
            // rec: sequential f32 dot over j, no FMA (np einsum order)
            float rec = 0.f;
#pragma unroll
            for (int j = 0; j < CO_; ++j) {
                float prod = L[j] * sp[cb][j][pp];
                rec = rec + prod;
            }

            // BN exactly as reference
            float t  = cv_c - meanf;
            float x  = t * invf;
            float xg = x * gm;
            float cx = xg + be;
            cx = cx + rec;

            // b_new = rho*b_t + (1-rho)*spk
            float rb  = rh * bt_c;
            float omr = 1.0f - rh;
            float os  = omr * sk_c;
            float bn  = rb + os;
            // new_thre = 0.1 + 1.8*b_new
            float tb = 1.8f * bn;
            float th = 0.1f + tb;
            // a_new = eta*a_curr + fb
            float ea = et * ac_c;
            float an = ea + fb_c;
            // sigmoid
            float sg = 1.0f / (1.0f + expf(-an));
            // soma_new = alpha*soma + (sig-0.5) + cx - thre*spk  (left-to-right)
            float as = al * so_c;
            float s5 = sg - 0.5f;
            float u1 = as + s5;
            float u2 = u1 + cx;
            float ts = th * sk_c;
            float sn = u2 - ts;

            outf[n]          = sn;
            outf[N_ + n]     = ((sn - th) > 0.0f) ? 1.f : 0.f;
            outf[2 * N_ + n] = an;
            outf[3 * N_ + n] = bn;                                // overwrites conv
        }
        sk_c = sk_n; cv_c = cv_n; bt_c = bt_n; ac_c = ac_n; fb_c = fb_n; so_c = so_n;
        n += (size_t)CP_;
    }
}

extern "C" void kernel_launch(void* const* d_in, const int* in_sizes, int n_in,
                              void* d_out, int out_size, void* d_ws, size_t ws_size,
                              hipStream_t stream)
{
    const float* ff        = (const float*)d_in[0];
    const float* fb        = (const float*)d_in[1];
    const float* soma_t    = (const float*)d_in[2];
    const float* spk_t     = (const float*)d_in[3];
    const float* a_curr    = (const float*)d_in[4];
    const float* b_t       = (const float*)d_in[5];
    const float* weight    = (const float*)d_in[6];
    const float* conv_bias = (const float*)d_in[7];
    const float* local_rec = (const float*)d_in[8];
    const float* gamma     = (const float*)d_in[9];
    const float* beta      = (const float*)d_in[10];
    const float* tau_m     = (const float*)d_in[11];
    const float* tau_adp   = (const float*)d_in[12];
    const float* tau_a     = (const float*)d_in[13];

    // ws: f64 partials then Mb (~0.5 MB total)
    double* part_sum = (double*)d_ws;                       // NBLK_CONV*CO_
    double* part_sq  = part_sum + (size_t)NBLK_CONV * CO_;  // NBLK_CONV*CO_
    float*  Mb       = (float*)(part_sq + (size_t)NBLK_CONV * CO_);  // 64

    float* outf = (float*)d_out;

    conv_kernel<<<dim3(8, 30, 8), 128, 0, stream>>>(
        ff, weight, conv_bias, outf, part_sum, part_sq);
    bn_finalize<<<dim3(CO_), 256, 0, stream>>>(part_sum, part_sq, Mb);
    lif_rec_kernel<<<dim3(512), 1024, 0, stream>>>(
        outf, local_rec, tau_m, tau_adp, tau_a, Mb, gamma, beta,
        fb, soma_t, spk_t, a_curr, b_t);
}

// Round 14
// 106.016 us; speedup vs baseline: 1.0753x; 1.0220x over previous
//
#include <hip/hip_runtime.h>
#include <math.h>

#pragma clang fp contract(off)

// Problem constants
#define B_   128
#define CI_  16
#define CO_  32
#define H_   32
#define W_   32
#define HO_  30
#define WO_  30
#define P_   900                 // HO*WO
#define CP_  (CO_*P_)            // 28800
#define N_   ((size_t)B_*CP_)    // 3686400 elements per tensor
#define NBLK_CONV (4*30*8)       // stat slots = 960 (UNCHANGED -> stats bitwise identical)
#define WSTRIDE_O 129600         // CI_*P_*9
#define WSTRIDE_C 8100           // P_*9
#define FFC_ (H_*W_)             // 1024  (channel stride in ff)
#define FFB_ (CI_*H_*W_)         // 16384 (batch stride in ff)
#define FFTOT_ (B_*FFB_)         // 2097152 total ff floats

// d_out layout (4*N_ floats): [0,N)=soma, [N,2N)=spike, [2N,3N)=a_new, [3N,4N)=b_new.
// Slot [3N,4N) temporarily holds the f32 conv value; LIF reads it before
// overwriting with b_new.

// async global->LDS. LDS dest is wave-uniform base + lane*width.
typedef __attribute__((address_space(1))) const unsigned int gas_uint;
typedef __attribute__((address_space(3))) unsigned int las_uint;
__device__ __forceinline__ void gload_lds4(const float* g, float* l) {
    __builtin_amdgcn_global_load_lds((gas_uint*)g, (las_uint*)l, 4, 0, 0);
}
__device__ __forceinline__ void gload_lds16(const float* g, float* l) {
    __builtin_amdgcn_global_load_lds((gas_uint*)g, (las_uint*)l, 16, 0, 0);
}

// ---------------------------------------------------------------------------
// Kernel 1: locally-connected conv. R13 with ONE change: o-INTERLEAVE.
// R13's residual 5.65e6 bank conflicts (== R5's) diagnosed at 16B-slot
// granularity: wk-read slot = (19*ol + 2w) mod 8 with ol = 2*og+oo -> ol
// always even for fixed oo -> only the 4 even slots used -> structural
// 4-way conflict regardless of pad stride. Fix: thread handles the two
// HALVES of the block's o-range: ol = 8*oo + og (o = os*16 + oo*8 + og).
// Then slot = (3*og + 4*wg2 + 2*ww) mod 8 -> all 8 slots hit exactly 2x
// (2-way = free, m136). k8-plane b32: banks 8og+2wg2+ww -> 16 lanes on 16
// distinct banks, conflict-free. Staging untouched (identity group->o map).
// Everything else R13: thread = 2o x 2w x 4b (21 B DS/out/ch), 128-thread
// blocks (2 waves), block = 16o x 8w x 16b, grid dim3(8,30,8) = 1920;
// weight groups padded to 76 floats; weight-sharing blocks 240 apart = 0
// mod 8 -> same XCD L2 (R6-proven).
// Stats: SAME 960x32 f64 slots, same per-lane sum order (j-major, ww
// minor), same d=4..32 shuffle tree -> slot values BITWISE identical ->
// outputs bit-identical. Accumulation (c outer, kh, kw; mul-add, no FMA).
// NOTE (R4/R6 lessons): no __launch_bounds__ VGPR cap, no pointer rotation,
// no >2-deep pipeline.
// ---------------------------------------------------------------------------
__global__ __launch_bounds__(128) void conv_kernel(
    const float* __restrict__ ff, const float* __restrict__ weight,
    const float* __restrict__ conv_bias, float* __restrict__ outf,
    double* __restrict__ part_sum, double* __restrict__ part_sumsq)
{
#pragma clang fp contract(off)
    const int tid = threadIdx.x;                     // 0..127
    const int og  = (tid & 3) | ((tid >> 6) << 2);   // 0..7
    const int wg2 = (tid >> 2) & 3;                  // 0..3
    const int bg  = (tid >> 4) & 3;                  // 0..3
    const int wave = tid >> 6;                       // 0..1
    const int wt = blockIdx.x & 3;      // 0..3
    const int os = blockIdx.x >> 2;     // 0..1  (o half: os*16 .. os*16+15)
    const int h  = blockIdx.y;          // 0..29
    const int b0 = blockIdx.z * 16;     // 16 batches per block
    const int w0 = wt * 8 + wg2 * 2;
    const bool val = !(wt == 3 && wg2 == 3);
    const int wwave = tid & ~63;        // wave-uniform lane-0 tid

    __shared__ float wgl[2][1344];      // 16 groups x 76 (64 data + 12 pad); k8 plane at 1216
    __shared__ float ffs[2][576];       // [buf][bb*36 + r*12 + cc]

    // ---- c-independent staging offsets (all in-bounds by construction) ----
    // weight dword s = q*128 + tid -> (ol = s>>6 in 0..15, w = (s>>3)&7, k = s&7)
    // LDS group ol holds o_global = os*16 + ol (identity map).
    int wq_off[8];
#pragma unroll
    for (int q = 0; q < 8; ++q) {
        int s = q * 128 + tid;          // 0..1023
        int ol = s >> 6, w = (s >> 3) & 7, k = s & 7;
        int colc = wt * 8 + w; if (colc > 29) colc = 29;   // edge clamp (garbage -> invalid threads only)
        wq_off[q] = (os * 16 + ol) * WSTRIDE_O + (h * WO_ + colc) * 9 + k;
    }
    int w8_off;
    {
        int ol = tid >> 3, w = tid & 7;
        int colc = wt * 8 + w; if (colc > 29) colc = 29;
        w8_off = (os * 16 + ol) * WSTRIDE_O + (h * WO_ + colc) * 9 + 8;
    }
    // ff chunk 1: dwords 4*tid (slots 0..127); chunk 2: dwords 512+4*tid (tid<16)
    int f_off, f_off2 = 0;
    {
        int s0 = 4 * tid;
        int bb = s0 / 36, rm = s0 % 36, r = rm / 12, cc0 = rm % 12;
        f_off = (b0 + bb) * FFB_ + (h + r) * W_ + wt * 8 + cc0;   // 16B-aligned
    }
    const bool f2on = (tid < 16);
    if (f2on) {
        int s0 = 512 + 4 * tid;
        int bb = s0 / 36, rm = s0 % 36, r = rm / 12, cc0 = rm % 12;
        f_off2 = (b0 + bb) * FFB_ + (h + r) * W_ + wt * 8 + cc0;  // 16B-aligned
    }

    float acc[2][2][4];                  // [oo][ww][j]
#pragma unroll
    for (int oo = 0; oo < 2; ++oo)
#pragma unroll
        for (int ww = 0; ww < 2; ++ww)
#pragma unroll
            for (int j = 0; j < 4; ++j) acc[oo][ww][j] = 0.f;

    auto stage = [&](int c, int buf) {
        const float* wsrc = weight + c * WSTRIDE_C;
#pragma unroll
        for (int q = 0; q < 8; ++q)
            gload_lds4(wsrc + wq_off[q], &wgl[buf][(2 * q + wave) * 76]);
        gload_lds4(wsrc + w8_off, &wgl[buf][1216 + (wave << 6)]);
        {
            int g = f_off + c * FFC_;
            if (g > FFTOT_ - 4) g = FFTOT_ - 4;   // corner clamp (garbage slots only)
            gload_lds16(ff + g, &ffs[buf][4 * wwave]);
        }
        if (f2on) {
            int g = f_off2 + c * FFC_;
            if (g > FFTOT_ - 4) g = FFTOT_ - 4;
            gload_lds16(ff + g, &ffs[buf][512]);  // lanes 0..15 -> dwords 512..575
        }
    };

    auto compute_c = [&](int buf) {
        float wk[2][2][9];
#pragma unroll
        for (int oo = 0; oo < 2; ++oo)
#pragma unroll
            for (int ww = 0; ww < 2; ++ww) {
                const int ol = oo * 8 + og, w = wg2 * 2 + ww;     // o-INTERLEAVE
                const float* wp = &wgl[buf][ol * 76 + w * 8];     // 304B group stride, 16B-aligned
                const float4 a = *reinterpret_cast<const float4*>(wp);
                const float4 b = *reinterpret_cast<const float4*>(wp + 4);
                wk[oo][ww][0] = a.x; wk[oo][ww][1] = a.y; wk[oo][ww][2] = a.z; wk[oo][ww][3] = a.w;
                wk[oo][ww][4] = b.x; wk[oo][ww][5] = b.y; wk[oo][ww][6] = b.z; wk[oo][ww][7] = b.w;
                wk[oo][ww][8] = wgl[buf][1216 + ol * 8 + w];
            }
#pragma unroll
        for (int j = 0; j < 4; ++j) {
            const int bb = bg * 4 + j;
            float fr[3][4];
#pragma unroll
            for (int r = 0; r < 3; ++r) {
                const float2 u = *reinterpret_cast<const float2*>(&ffs[buf][bb * 36 + r * 12 + wg2 * 2]);
                const float2 v = *reinterpret_cast<const float2*>(&ffs[buf][bb * 36 + r * 12 + wg2 * 2 + 2]);
                fr[r][0] = u.x; fr[r][1] = u.y; fr[r][2] = v.x; fr[r][3] = v.y;
            }
#pragma unroll
            for (int oo = 0; oo < 2; ++oo)
#pragma unroll
                for (int ww = 0; ww < 2; ++ww) {
                    float a = acc[oo][ww][j];
#pragma unroll
                    for (int kh = 0; kh < 3; ++kh)
#pragma unroll
                        for (int kw = 0; kw < 3; ++kw) {
                            float prod = wk[oo][ww][kh * 3 + kw] * fr[kh][ww + kw];
                            a = a + prod;      // no FMA, (c,kh,kw) order
                        }
                    acc[oo][ww][j] = a;
                }
        }
    };

    stage(0, 0);
    __syncthreads();
    for (int cs = 0; cs < CI_; cs += 2) {
        if (cs + 1 < CI_) stage(cs + 1, 1);   // prefetch overlaps compute
        compute_c(0);
        __syncthreads();
        if (cs + 2 < CI_) stage(cs + 2, 0);
        compute_c(1);
        __syncthreads();
    }

    // epilogue: bias, park conv values, exact f64 per-slot per-channel stats
    double s1[2] = {0.0, 0.0}, s2[2] = {0.0, 0.0};
    if (val) {
#pragma unroll
        for (int oo = 0; oo < 2; ++oo) {
            const int o = os * 16 + oo * 8 + og;         // o-INTERLEAVE
            const int pidx = o * P_ + h * WO_ + w0;
            const float2 bi = *reinterpret_cast<const float2*>(conv_bias + pidx);
#pragma unroll
            for (int j = 0; j < 4; ++j) {
                const int b = b0 + bg * 4 + j;
                const size_t n = (size_t)b * CP_ + (size_t)pidx;
                float v0 = acc[oo][0][j] + bi.x;     // f32, same as ref
                float v1 = acc[oo][1][j] + bi.y;
                *reinterpret_cast<float2*>(outf + 3 * N_ + n) = make_float2(v0, v1);
                double d0 = (double)v0, d1 = (double)v1;
                s1[oo] += d0; s2[oo] += d0 * d0;
                s1[oo] += d1; s2[oo] += d1 * d1;
            }
        }
    }
    // deterministic reduce over the 16 lanes (stride 4) sharing og
#pragma unroll
    for (int d = 4; d < 64; d <<= 1) {
#pragma unroll
        for (int oo = 0; oo < 2; ++oo) {
            s1[oo] += __shfl_xor(s1[oo], d);
            s2[oo] += __shfl_xor(s2[oo], d);
        }
    }
    if ((tid & 60) == 0) {               // wg2==0 && bg==0: tid in {0..3, 64..67}
        int blk = (blockIdx.z * 30 + blockIdx.y) * 4 + wt;   // 0..959 (same slots)
#pragma unroll
        for (int oo = 0; oo < 2; ++oo) {
            const int o = os * 16 + oo * 8 + og;
            part_sum  [blk * CO_ + o] = s1[oo];
            part_sumsq[blk * CO_ + o] = s2[oo];
        }
    }
}

// ---------------------------------------------------------------------------
// Kernel 2: BN finalize — deterministic f64 reduction of partials (960
// slots), then f32 mean / inv_std per channel. UNCHANGED.
// ---------------------------------------------------------------------------
__global__ __launch_bounds__(256) void bn_finalize(
    const double* __restrict__ part_sum, const double* __restrict__ part_sumsq,
    float* __restrict__ Mb)
{
#pragma clang fp contract(off)
    const int o = blockIdx.x;
    const int tid = threadIdx.x;
    double s1 = 0.0, s2 = 0.0;
    for (int i = tid; i < NBLK_CONV; i += 256) {
        s1 += part_sum[i * CO_ + o];
        s2 += part_sumsq[i * CO_ + o];
    }
    __shared__ double r1[256], r2[256];
    r1[tid] = s1; r2[tid] = s2;
    __syncthreads();
    for (int s = 128; s > 0; s >>= 1) {
        if (tid < s) { r1[tid] += r1[tid + s]; r2[tid] += r2[tid + s]; }
        __syncthreads();
    }
    if (tid == 0) {
        const double cnt = (double)(B_ * (size_t)P_);
        double mean = r1[0] / cnt;
        float meanf = (float)mean;
        double md = (double)meanf;
        double var = r2[0] / cnt - 2.0 * md * (r1[0] / cnt) + md * md;
        float varf = (float)var;
        float invf = 1.0f / sqrtf(varf + 1e-5f);
        Mb[o]       = meanf;
        Mb[CO_ + o] = invf;
    }
}

// ---------------------------------------------------------------------------
// Kernel 3: fused recurrent-bmm + LIF. R7/R11 VERBATIM (champion component):
// LDS spike tile, parity double-buffer, register prefetch, lgkmcnt(0)-only
// barrier; 1024 thr = 32 i x 32 p; XCD-grouped 1D grid (512 blocks): pt
// determines D&7, so the 16 b-blocks sharing a local_rec/tau p-slice land
// on one XCD's L2.
// ---------------------------------------------------------------------------
__global__ __launch_bounds__(1024) void lif_rec_kernel(
    float* __restrict__ outf, const float* __restrict__ local_rec,
    const float* __restrict__ tau_m, const float* __restrict__ tau_adp,
    const float* __restrict__ tau_a, const float* __restrict__ Mb,
    const float* __restrict__ gamma, const float* __restrict__ beta,
    const float* __restrict__ fb, const float* __restrict__ soma_t,
    const float* __restrict__ spk_t, const float* __restrict__ a_curr,
    const float* __restrict__ b_t)
{
#pragma clang fp contract(off)
    const int D    = blockIdx.x;
    const int pt8  = D & 7;
    const int rest = D >> 3;
    const int by   = rest & 15;
    const int ptq  = rest >> 4;          // 0..3
    const int pt   = ptq * 8 + pt8;      // 0..31
    if (pt >= 29) return;                // 29 p-tiles cover P_=900

    const int tid = threadIdx.x;
    const int pp  = tid & 31;
    const int i   = tid >> 5;            // channel 0..31
    const int p   = pt * 32 + pp;
    const bool pv = (p < P_);
    const int b0  = by * 8;

    float L[32];
    float meanf = 0.f, invf = 0.f, gm = 0.f, be = 0.f;
    float al = 0.f, rh = 0.f, et = 0.f;
    int rem = 0;
    if (pv) {
        const float4* lp = reinterpret_cast<const float4*>(local_rec + (size_t)p * (CO_ * CO_) + i * CO_);
#pragma unroll
        for (int q = 0; q < 8; ++q) {
            float4 v = lp[q];
            L[4 * q] = v.x; L[4 * q + 1] = v.y; L[4 * q + 2] = v.z; L[4 * q + 3] = v.w;
        }
        rem = i * P_ + p;
        meanf = Mb[i]; invf = Mb[CO_ + i];
        gm = gamma[i]; be = beta[i];
        // identical f32 ops to the original tau table: f32 divide then f32 exp
        al = expf(-0.5f / tau_m[rem]);
        rh = expf(-0.5f / tau_adp[rem]);
        et = expf(-0.5f / tau_a[rem]);
    }

    __shared__ float sp[2][CO_][32];

    // prologue: iteration-0 operands into registers
    size_t n = (size_t)b0 * CP_ + (size_t)rem;
    float sk_c = 0.f, cv_c = 0.f, bt_c = 0.f, ac_c = 0.f, fb_c = 0.f, so_c = 0.f;
    if (pv) {
        sk_c = spk_t[n]; cv_c = outf[3 * N_ + n]; bt_c = b_t[n];
        ac_c = a_curr[n]; fb_c = fb[n]; so_c = soma_t[n];
    }

#pragma unroll
    for (int bb = 0; bb < 8; ++bb) {
        const int cb = bb & 1;
        if (pv) sp[cb][i][pp] = sk_c;
        // prefetch next iteration BEFORE the barrier (stays in flight: the
        // raw barrier below drains lgkmcnt only, not vmcnt)
        float sk_n = 0.f, cv_n = 0.f, bt_n = 0.f, ac_n = 0.f, fb_n = 0.f, so_n = 0.f;
        if (bb + 1 < 8 && pv) {
            const size_t nn = n + (size_t)CP_;
            sk_n = spk_t[nn]; cv_n = outf[3 * N_ + nn]; bt_n = b_t[nn];
            ac_n = a_curr[nn]; fb_n = fb[nn]; so_n = soma_t[nn];
        }
        asm volatile("s_waitcnt lgkmcnt(0)\n\ts_barrier" ::: "memory");
        if (pv) {
            // rec: sequential f32 dot over j, no FMA (np einsum order)
            float rec = 0.f;
#pragma unroll
            for (int j = 0; j < CO_; ++j) {
                float prod = L[j] * sp[cb][j][pp];
                rec = rec + prod;
            }

            // BN exactly as reference
            float t  = cv_c - meanf;
            float x  = t * invf;
            float xg = x * gm;
            float cx = xg + be;
            cx = cx + rec;

            // b_new = rho*b_t + (1-rho)*spk
            float rb  = rh * bt_c;
            float omr = 1.0f - rh;
            float os  = omr * sk_c;
            float bn  = rb + os;
            // new_thre = 0.1 + 1.8*b_new
            float tb = 1.8f * bn;
            float th = 0.1f + tb;
            // a_new = eta*a_curr + fb
            float ea = et * ac_c;
            float an = ea + fb_c;
            // sigmoid
            float sg = 1.0f / (1.0f + expf(-an));
            // soma_new = alpha*soma + (sig-0.5) + cx - thre*spk  (left-to-right)
            float as = al * so_c;
            float s5 = sg - 0.5f;
            float u1 = as + s5;
            float u2 = u1 + cx;
            float ts = th * sk_c;
            float sn = u2 - ts;

            outf[n]          = sn;
            outf[N_ + n]     = ((sn - th) > 0.0f) ? 1.f : 0.f;
            outf[2 * N_ + n] = an;
            outf[3 * N_ + n] = bn;                                // overwrites conv
        }
        sk_c = sk_n; cv_c = cv_n; bt_c = bt_n; ac_c = ac_n; fb_c = fb_n; so_c = so_n;
        n += (size_t)CP_;
    }
}

extern "C" void kernel_launch(void* const* d_in, const int* in_sizes, int n_in,
                              void* d_out, int out_size, void* d_ws, size_t ws_size,
                              hipStream_t stream)
{
    const float* ff        = (const float*)d_in[0];
    const float* fb        = (const float*)d_in[1];
    const float* soma_t    = (const float*)d_in[2];
    const float* spk_t     = (const float*)d_in[3];
    const float* a_curr    = (const float*)d_in[4];
    const float* b_t       = (const float*)d_in[5];
    const float* weight    = (const float*)d_in[6];
    const float* conv_bias = (const float*)d_in[7];
    const float* local_rec = (const float*)d_in[8];
    const float* gamma     = (const float*)d_in[9];
    const float* beta      = (const float*)d_in[10];
    const float* tau_m     = (const float*)d_in[11];
    const float* tau_adp   = (const float*)d_in[12];
    const float* tau_a     = (const float*)d_in[13];

    // ws: f64 partials then Mb (~0.5 MB total)
    double* part_sum = (double*)d_ws;                       // NBLK_CONV*CO_
    double* part_sq  = part_sum + (size_t)NBLK_CONV * CO_;  // NBLK_CONV*CO_
    float*  Mb       = (float*)(part_sq + (size_t)NBLK_CONV * CO_);  // 64

    float* outf = (float*)d_out;

    conv_kernel<<<dim3(8, 30, 8), 128, 0, stream>>>(
        ff, weight, conv_bias, outf, part_sum, part_sq);
    bn_finalize<<<dim3(CO_), 256, 0, stream>>>(part_sum, part_sq, Mb);
    lif_rec_kernel<<<dim3(512), 1024, 0, stream>>>(
        outf, local_rec, tau_m, tau_adp, tau_a, Mb, gamma, beta,
        fb, soma_t, spk_t, a_curr, b_t);
}

// Round 15
// 105.224 us; speedup vs baseline: 1.0834x; 1.0075x over previous
//
#include <hip/hip_runtime.h>
#include <math.h>

#pragma clang fp contract(off)

// Problem constants
#define B_   128
#define CI_  16
#define CO_  32
#define H_   32
#define W_   32
#define HO_  30
#define WO_  30
#define P_   900                 // HO*WO
#define CP_  (CO_*P_)            // 28800
#define N_   ((size_t)B_*CP_)    // 3686400 elements per tensor
#define NBLK_CONV (4*30*8)       // stat slots = 960 (UNCHANGED -> stats bitwise identical)
#define WSTRIDE_O 129600         // CI_*P_*9
#define WSTRIDE_C 8100           // P_*9
#define FFC_ (H_*W_)             // 1024  (channel stride in ff)
#define FFB_ (CI_*H_*W_)         // 16384 (batch stride in ff)
#define FFTOT_ (B_*FFB_)         // 2097152 total ff floats

// d_out layout (4*N_ floats): [0,N)=soma, [N,2N)=spike, [2N,3N)=a_new, [3N,4N)=b_new.
// Slot [3N,4N) temporarily holds the f32 conv value; LIF reads it before
// overwriting with b_new.

// async global->LDS. LDS dest is wave-uniform base + lane*width.
typedef __attribute__((address_space(1))) const unsigned int gas_uint;
typedef __attribute__((address_space(3))) unsigned int las_uint;
__device__ __forceinline__ void gload_lds4(const float* g, float* l) {
    __builtin_amdgcn_global_load_lds((gas_uint*)g, (las_uint*)l, 4, 0, 0);
}
__device__ __forceinline__ void gload_lds16(const float* g, float* l) {
    __builtin_amdgcn_global_load_lds((gas_uint*)g, (las_uint*)l, 16, 0, 0);
}

// ---------------------------------------------------------------------------
// Kernel 1: locally-connected conv. R14 VERBATIM (champion component, <67us):
// o-INTERLEAVE (ol = 8*oo + og -> wk-read 16B-slots all 8 hit exactly 2x =
// free; k8 b32 conflict-free), thread = 2o x 2w x 4b (21 B DS/out/ch),
// 128-thread blocks, block = 16o x 8w x 16b, grid dim3(8,30,8) = 1920;
// weight groups padded to 76 floats; weight-sharing blocks 240 apart = 0
// mod 8 -> same XCD L2. Stats: 960x32 f64 slots, bitwise identical.
// Accumulation (c outer, kh, kw; mul-add, no FMA).
// NOTE (R4/R6 lessons): no __launch_bounds__ VGPR cap, no pointer rotation,
// no >2-deep pipeline.
// ---------------------------------------------------------------------------
__global__ __launch_bounds__(128) void conv_kernel(
    const float* __restrict__ ff, const float* __restrict__ weight,
    const float* __restrict__ conv_bias, float* __restrict__ outf,
    double* __restrict__ part_sum, double* __restrict__ part_sumsq)
{
#pragma clang fp contract(off)
    const int tid = threadIdx.x;                     // 0..127
    const int og  = (tid & 3) | ((tid >> 6) << 2);   // 0..7
    const int wg2 = (tid >> 2) & 3;                  // 0..3
    const int bg  = (tid >> 4) & 3;                  // 0..3
    const int wave = tid >> 6;                       // 0..1
    const int wt = blockIdx.x & 3;      // 0..3
    const int os = blockIdx.x >> 2;     // 0..1  (o half: os*16 .. os*16+15)
    const int h  = blockIdx.y;          // 0..29
    const int b0 = blockIdx.z * 16;     // 16 batches per block
    const int w0 = wt * 8 + wg2 * 2;
    const bool val = !(wt == 3 && wg2 == 3);
    const int wwave = tid & ~63;        // wave-uniform lane-0 tid

    __shared__ float wgl[2][1344];      // 16 groups x 76 (64 data + 12 pad); k8 plane at 1216
    __shared__ float ffs[2][576];       // [buf][bb*36 + r*12 + cc]

    // ---- c-independent staging offsets (all in-bounds by construction) ----
    int wq_off[8];
#pragma unroll
    for (int q = 0; q < 8; ++q) {
        int s = q * 128 + tid;          // 0..1023
        int ol = s >> 6, w = (s >> 3) & 7, k = s & 7;
        int colc = wt * 8 + w; if (colc > 29) colc = 29;   // edge clamp (garbage -> invalid threads only)
        wq_off[q] = (os * 16 + ol) * WSTRIDE_O + (h * WO_ + colc) * 9 + k;
    }
    int w8_off;
    {
        int ol = tid >> 3, w = tid & 7;
        int colc = wt * 8 + w; if (colc > 29) colc = 29;
        w8_off = (os * 16 + ol) * WSTRIDE_O + (h * WO_ + colc) * 9 + 8;
    }
    int f_off, f_off2 = 0;
    {
        int s0 = 4 * tid;
        int bb = s0 / 36, rm = s0 % 36, r = rm / 12, cc0 = rm % 12;
        f_off = (b0 + bb) * FFB_ + (h + r) * W_ + wt * 8 + cc0;   // 16B-aligned
    }
    const bool f2on = (tid < 16);
    if (f2on) {
        int s0 = 512 + 4 * tid;
        int bb = s0 / 36, rm = s0 % 36, r = rm / 12, cc0 = rm % 12;
        f_off2 = (b0 + bb) * FFB_ + (h + r) * W_ + wt * 8 + cc0;  // 16B-aligned
    }

    float acc[2][2][4];                  // [oo][ww][j]
#pragma unroll
    for (int oo = 0; oo < 2; ++oo)
#pragma unroll
        for (int ww = 0; ww < 2; ++ww)
#pragma unroll
            for (int j = 0; j < 4; ++j) acc[oo][ww][j] = 0.f;

    auto stage = [&](int c, int buf) {
        const float* wsrc = weight + c * WSTRIDE_C;
#pragma unroll
        for (int q = 0; q < 8; ++q)
            gload_lds4(wsrc + wq_off[q], &wgl[buf][(2 * q + wave) * 76]);
        gload_lds4(wsrc + w8_off, &wgl[buf][1216 + (wave << 6)]);
        {
            int g = f_off + c * FFC_;
            if (g > FFTOT_ - 4) g = FFTOT_ - 4;   // corner clamp (garbage slots only)
            gload_lds16(ff + g, &ffs[buf][4 * wwave]);
        }
        if (f2on) {
            int g = f_off2 + c * FFC_;
            if (g > FFTOT_ - 4) g = FFTOT_ - 4;
            gload_lds16(ff + g, &ffs[buf][512]);  // lanes 0..15 -> dwords 512..575
        }
    };

    auto compute_c = [&](int buf) {
        float wk[2][2][9];
#pragma unroll
        for (int oo = 0; oo < 2; ++oo)
#pragma unroll
            for (int ww = 0; ww < 2; ++ww) {
                const int ol = oo * 8 + og, w = wg2 * 2 + ww;     // o-INTERLEAVE
                const float* wp = &wgl[buf][ol * 76 + w * 8];     // 304B group stride, 16B-aligned
                const float4 a = *reinterpret_cast<const float4*>(wp);
                const float4 b = *reinterpret_cast<const float4*>(wp + 4);
                wk[oo][ww][0] = a.x; wk[oo][ww][1] = a.y; wk[oo][ww][2] = a.z; wk[oo][ww][3] = a.w;
                wk[oo][ww][4] = b.x; wk[oo][ww][5] = b.y; wk[oo][ww][6] = b.z; wk[oo][ww][7] = b.w;
                wk[oo][ww][8] = wgl[buf][1216 + ol * 8 + w];
            }
#pragma unroll
        for (int j = 0; j < 4; ++j) {
            const int bb = bg * 4 + j;
            float fr[3][4];
#pragma unroll
            for (int r = 0; r < 3; ++r) {
                const float2 u = *reinterpret_cast<const float2*>(&ffs[buf][bb * 36 + r * 12 + wg2 * 2]);
                const float2 v = *reinterpret_cast<const float2*>(&ffs[buf][bb * 36 + r * 12 + wg2 * 2 + 2]);
                fr[r][0] = u.x; fr[r][1] = u.y; fr[r][2] = v.x; fr[r][3] = v.y;
            }
#pragma unroll
            for (int oo = 0; oo < 2; ++oo)
#pragma unroll
                for (int ww = 0; ww < 2; ++ww) {
                    float a = acc[oo][ww][j];
#pragma unroll
                    for (int kh = 0; kh < 3; ++kh)
#pragma unroll
                        for (int kw = 0; kw < 3; ++kw) {
                            float prod = wk[oo][ww][kh * 3 + kw] * fr[kh][ww + kw];
                            a = a + prod;      // no FMA, (c,kh,kw) order
                        }
                    acc[oo][ww][j] = a;
                }
        }
    };

    stage(0, 0);
    __syncthreads();
    for (int cs = 0; cs < CI_; cs += 2) {
        if (cs + 1 < CI_) stage(cs + 1, 1);   // prefetch overlaps compute
        compute_c(0);
        __syncthreads();
        if (cs + 2 < CI_) stage(cs + 2, 0);
        compute_c(1);
        __syncthreads();
    }

    // epilogue: bias, park conv values, exact f64 per-slot per-channel stats
    double s1[2] = {0.0, 0.0}, s2[2] = {0.0, 0.0};
    if (val) {
#pragma unroll
        for (int oo = 0; oo < 2; ++oo) {
            const int o = os * 16 + oo * 8 + og;         // o-INTERLEAVE
            const int pidx = o * P_ + h * WO_ + w0;
            const float2 bi = *reinterpret_cast<const float2*>(conv_bias + pidx);
#pragma unroll
            for (int j = 0; j < 4; ++j) {
                const int b = b0 + bg * 4 + j;
                const size_t n = (size_t)b * CP_ + (size_t)pidx;
                float v0 = acc[oo][0][j] + bi.x;     // f32, same as ref
                float v1 = acc[oo][1][j] + bi.y;
                *reinterpret_cast<float2*>(outf + 3 * N_ + n) = make_float2(v0, v1);
                double d0 = (double)v0, d1 = (double)v1;
                s1[oo] += d0; s2[oo] += d0 * d0;
                s1[oo] += d1; s2[oo] += d1 * d1;
            }
        }
    }
    // deterministic reduce over the 16 lanes (stride 4) sharing og
#pragma unroll
    for (int d = 4; d < 64; d <<= 1) {
#pragma unroll
        for (int oo = 0; oo < 2; ++oo) {
            s1[oo] += __shfl_xor(s1[oo], d);
            s2[oo] += __shfl_xor(s2[oo], d);
        }
    }
    if ((tid & 60) == 0) {               // wg2==0 && bg==0: tid in {0..3, 64..67}
        int blk = (blockIdx.z * 30 + blockIdx.y) * 4 + wt;   // 0..959 (same slots)
#pragma unroll
        for (int oo = 0; oo < 2; ++oo) {
            const int o = os * 16 + oo * 8 + og;
            part_sum  [blk * CO_ + o] = s1[oo];
            part_sumsq[blk * CO_ + o] = s2[oo];
        }
    }
}

// ---------------------------------------------------------------------------
// Kernel 2: BN finalize — deterministic f64 reduction of partials (960
// slots), then f32 mean / inv_std per channel. UNCHANGED.
// ---------------------------------------------------------------------------
__global__ __launch_bounds__(256) void bn_finalize(
    const double* __restrict__ part_sum, const double* __restrict__ part_sumsq,
    float* __restrict__ Mb)
{
#pragma clang fp contract(off)
    const int o = blockIdx.x;
    const int tid = threadIdx.x;
    double s1 = 0.0, s2 = 0.0;
    for (int i = tid; i < NBLK_CONV; i += 256) {
        s1 += part_sum[i * CO_ + o];
        s2 += part_sumsq[i * CO_ + o];
    }
    __shared__ double r1[256], r2[256];
    r1[tid] = s1; r2[tid] = s2;
    __syncthreads();
    for (int s = 128; s > 0; s >>= 1) {
        if (tid < s) { r1[tid] += r1[tid + s]; r2[tid] += r2[tid + s]; }
        __syncthreads();
    }
    if (tid == 0) {
        const double cnt = (double)(B_ * (size_t)P_);
        double mean = r1[0] / cnt;
        float meanf = (float)mean;
        double md = (double)meanf;
        double var = r2[0] / cnt - 2.0 * md * (r1[0] / cnt) + md * md;
        float varf = (float)var;
        float invf = 1.0f / sqrtf(varf + 1e-5f);
        Mb[o]       = meanf;
        Mb[CO_ + o] = invf;
    }
}

// ---------------------------------------------------------------------------
// Kernel 3: fused recurrent-bmm + LIF. Champion (R7/R11) mechanism with ONE
// change: 2 batches per barrier round, 4 spike tiles (16 KB). Rounds 8 -> 4:
// each round stages two tiles (per-lane ds_write, proven), prefetches the
// NEXT two batches' operands (stay in flight: lgkmcnt-only barrier), then
// computes both batches -- a 2x longer compute phase to hide the 12
// in-flight loads, and half the barrier convoys.
// Safety (tile-reuse induction): tiles t written in round r were last READ
// in round r-2; those ds_read values are consumed by VALU in round r-2's
// compute, which precedes each wave's bar(r-1) in program order; the write
// in round r follows bar(r-1) -> no wave can write a tile another wave has
// yet to read. Fully unrolled r -> tile indices are literals (rule #20).
// Geometry/decode/math identical to champion => bit-identical outputs.
// ---------------------------------------------------------------------------
__global__ __launch_bounds__(1024) void lif_rec_kernel(
    float* __restrict__ outf, const float* __restrict__ local_rec,
    const float* __restrict__ tau_m, const float* __restrict__ tau_adp,
    const float* __restrict__ tau_a, const float* __restrict__ Mb,
    const float* __restrict__ gamma, const float* __restrict__ beta,
    const float* __restrict__ fb, const float* __restrict__ soma_t,
    const float* __restrict__ spk_t, const float* __restrict__ a_curr,
    const float* __restrict__ b_t)
{
#pragma clang fp contract(off)
    const int D    = blockIdx.x;
    const int pt8  = D & 7;
    const int rest = D >> 3;
    const int by   = rest & 15;
    const int ptq  = rest >> 4;          // 0..3
    const int pt   = ptq * 8 + pt8;      // 0..31
    if (pt >= 29) return;                // 29 p-tiles cover P_=900

    const int tid = threadIdx.x;
    const int pp  = tid & 31;
    const int i   = tid >> 5;            // channel 0..31
    const int p   = pt * 32 + pp;
    const bool pv = (p < P_);
    const int b0  = by * 8;

    float L[32];
    float meanf = 0.f, invf = 0.f, gm = 0.f, be = 0.f;
    float al = 0.f, rh = 0.f, et = 0.f;
    int rem = 0;
    if (pv) {
        const float4* lp = reinterpret_cast<const float4*>(local_rec + (size_t)p * (CO_ * CO_) + i * CO_);
#pragma unroll
        for (int q = 0; q < 8; ++q) {
            float4 v = lp[q];
            L[4 * q] = v.x; L[4 * q + 1] = v.y; L[4 * q + 2] = v.z; L[4 * q + 3] = v.w;
        }
        rem = i * P_ + p;
        meanf = Mb[i]; invf = Mb[CO_ + i];
        gm = gamma[i]; be = beta[i];
        // identical f32 ops to the original tau table: f32 divide then f32 exp
        al = expf(-0.5f / tau_m[rem]);
        rh = expf(-0.5f / tau_adp[rem]);
        et = expf(-0.5f / tau_a[rem]);
    }
    const float omr = 1.0f - rh;

    __shared__ float sp[4][CO_][32];     // 16 KB: two double-buffered tile PAIRS

    // prologue: operands for batches b0, b0+1
    size_t n = (size_t)b0 * CP_ + (size_t)rem;
    float sk0 = 0.f, cv0 = 0.f, bt0 = 0.f, ac0 = 0.f, fb0 = 0.f, so0 = 0.f;
    float sk1 = 0.f, cv1 = 0.f, bt1 = 0.f, ac1 = 0.f, fb1 = 0.f, so1 = 0.f;
    if (pv) {
        sk0 = spk_t[n];       cv0 = outf[3 * N_ + n];       bt0 = b_t[n];
        ac0 = a_curr[n];      fb0 = fb[n];                  so0 = soma_t[n];
        const size_t n1 = n + (size_t)CP_;
        sk1 = spk_t[n1];      cv1 = outf[3 * N_ + n1];      bt1 = b_t[n1];
        ac1 = a_curr[n1];     fb1 = fb[n1];                 so1 = soma_t[n1];
    }

#pragma unroll
    for (int r = 0; r < 4; ++r) {
        const int t0 = (r & 1) * 2;      // literal after unroll
        if (pv) {
            sp[t0][i][pp]     = sk0;
            sp[t0 + 1][i][pp] = sk1;
        }
        // prefetch operands for batches 2r+2, 2r+3 BEFORE the barrier
        // (vmcnt ops stay in flight: the raw barrier drains lgkmcnt only)
        float sk0n = 0.f, cv0n = 0.f, bt0n = 0.f, ac0n = 0.f, fb0n = 0.f, so0n = 0.f;
        float sk1n = 0.f, cv1n = 0.f, bt1n = 0.f, ac1n = 0.f, fb1n = 0.f, so1n = 0.f;
        if (r < 3 && pv) {
            const size_t n2 = n + (size_t)(2 * CP_);
            const size_t n3 = n + (size_t)(3 * CP_);
            sk0n = spk_t[n2];  cv0n = outf[3 * N_ + n2];  bt0n = b_t[n2];
            ac0n = a_curr[n2]; fb0n = fb[n2];             so0n = soma_t[n2];
            sk1n = spk_t[n3];  cv1n = outf[3 * N_ + n3];  bt1n = b_t[n3];
            ac1n = a_curr[n3]; fb1n = fb[n3];             so1n = soma_t[n3];
        }
        asm volatile("s_waitcnt lgkmcnt(0)\n\ts_barrier" ::: "memory");
        if (pv) {
            // ---- batch 2r ----
            {
                float rec = 0.f;
#pragma unroll
                for (int j = 0; j < CO_; ++j) {
                    float prod = L[j] * sp[t0][j][pp];
                    rec = rec + prod;
                }
                float t  = cv0 - meanf;
                float x  = t * invf;
                float xg = x * gm;
                float cx = xg + be;
                cx = cx + rec;
                float rb  = rh * bt0;
                float os  = omr * sk0;
                float bn  = rb + os;
                float tb = 1.8f * bn;
                float th = 0.1f + tb;
                float ea = et * ac0;
                float an = ea + fb0;
                float sg = 1.0f / (1.0f + expf(-an));
                float as = al * so0;
                float s5 = sg - 0.5f;
                float u1 = as + s5;
                float u2 = u1 + cx;
                float ts = th * sk0;
                float sn = u2 - ts;
                outf[n]          = sn;
                outf[N_ + n]     = ((sn - th) > 0.0f) ? 1.f : 0.f;
                outf[2 * N_ + n] = an;
                outf[3 * N_ + n] = bn;
            }
            // ---- batch 2r+1 ----
            {
                const size_t n1 = n + (size_t)CP_;
                float rec = 0.f;
#pragma unroll
                for (int j = 0; j < CO_; ++j) {
                    float prod = L[j] * sp[t0 + 1][j][pp];
                    rec = rec + prod;
                }
                float t  = cv1 - meanf;
                float x  = t * invf;
                float xg = x * gm;
                float cx = xg + be;
                cx = cx + rec;
                float rb  = rh * bt1;
                float os  = omr * sk1;
                float bn  = rb + os;
                float tb = 1.8f * bn;
                float th = 0.1f + tb;
                float ea = et * ac1;
                float an = ea + fb1;
                float sg = 1.0f / (1.0f + expf(-an));
                float as = al * so1;
                float s5 = sg - 0.5f;
                float u1 = as + s5;
                float u2 = u1 + cx;
                float ts = th * sk1;
                float sn = u2 - ts;
                outf[n1]          = sn;
                outf[N_ + n1]     = ((sn - th) > 0.0f) ? 1.f : 0.f;
                outf[2 * N_ + n1] = an;
                outf[3 * N_ + n1] = bn;
            }
        }
        sk0 = sk0n; cv0 = cv0n; bt0 = bt0n; ac0 = ac0n; fb0 = fb0n; so0 = so0n;
        sk1 = sk1n; cv1 = cv1n; bt1 = bt1n; ac1 = ac1n; fb1 = fb1n; so1 = so1n;
        n += (size_t)(2 * CP_);
    }
}

extern "C" void kernel_launch(void* const* d_in, const int* in_sizes, int n_in,
                              void* d_out, int out_size, void* d_ws, size_t ws_size,
                              hipStream_t stream)
{
    const float* ff        = (const float*)d_in[0];
    const float* fb        = (const float*)d_in[1];
    const float* soma_t    = (const float*)d_in[2];
    const float* spk_t     = (const float*)d_in[3];
    const float* a_curr    = (const float*)d_in[4];
    const float* b_t       = (const float*)d_in[5];
    const float* weight    = (const float*)d_in[6];
    const float* conv_bias = (const float*)d_in[7];
    const float* local_rec = (const float*)d_in[8];
    const float* gamma     = (const float*)d_in[9];
    const float* beta      = (const float*)d_in[10];
    const float* tau_m     = (const float*)d_in[11];
    const float* tau_adp   = (const float*)d_in[12];
    const float* tau_a     = (const float*)d_in[13];

    // ws: f64 partials then Mb (~0.5 MB total)
    double* part_sum = (double*)d_ws;                       // NBLK_CONV*CO_
    double* part_sq  = part_sum + (size_t)NBLK_CONV * CO_;  // NBLK_CONV*CO_
    float*  Mb       = (float*)(part_sq + (size_t)NBLK_CONV * CO_);  // 64

    float* outf = (float*)d_out;

    conv_kernel<<<dim3(8, 30, 8), 128, 0, stream>>>(
        ff, weight, conv_bias, outf, part_sum, part_sq);
    bn_finalize<<<dim3(CO_), 256, 0, stream>>>(part_sum, part_sq, Mb);
    lif_rec_kernel<<<dim3(512), 1024, 0, stream>>>(
        outf, local_rec, tau_m, tau_adp, tau_a, Mb, gamma, beta,
        fb, soma_t, spk_t, a_curr, b_t);
}

// Round 17
// 104.568 us; speedup vs baseline: 1.0902x; 1.0063x over previous
//
#include <hip/hip_runtime.h>
#include <math.h>

#pragma clang fp contract(off)

// Problem constants
#define B_   128
#define CI_  16
#define CO_  32
#define H_   32
#define W_   32
#define HO_  30
#define WO_  30
#define P_   900                 // HO*WO
#define CP_  (CO_*P_)            // 28800
#define N_   ((size_t)B_*CP_)    // 3686400 elements per tensor
#define NBLK_CONV (4*30*8)       // stat slots = 960 (UNCHANGED -> stats bitwise identical)
#define WSTRIDE_O 129600         // CI_*P_*9
#define WSTRIDE_C 8100           // P_*9
#define FFC_ (H_*W_)             // 1024  (channel stride in ff)
#define FFB_ (CI_*H_*W_)         // 16384 (batch stride in ff)
#define FFTOT_ (B_*FFB_)         // 2097152 total ff floats

// d_out layout (4*N_ floats): [0,N)=soma, [N,2N)=spike, [2N,3N)=a_new, [3N,4N)=b_new.
// Slot [3N,4N) temporarily holds the f32 conv value; LIF reads it before
// overwriting with b_new.

// async global->LDS. LDS dest is wave-uniform base + lane*width.
typedef __attribute__((address_space(1))) const unsigned int gas_uint;
typedef __attribute__((address_space(3))) unsigned int las_uint;
__device__ __forceinline__ void gload_lds4(const float* g, float* l) {
    __builtin_amdgcn_global_load_lds((gas_uint*)g, (las_uint*)l, 4, 0, 0);
}
__device__ __forceinline__ void gload_lds16(const float* g, float* l) {
    __builtin_amdgcn_global_load_lds((gas_uint*)g, (las_uint*)l, 16, 0, 0);
}

// ---------------------------------------------------------------------------
// Kernel 1: locally-connected conv — SINGLE-WAVE BLOCKS (R16 retry; R16's
// failure was a staging/read LAYOUT MISMATCH: staging decoded in-group
// position as w*9+k while compute reads w*8+k (k8 in a separate plane).
// Fixed: data at r<64 with w=r>>3, k=r&7; r 64..75 are pads (src=0, never
// read). Rule-21 lesson: with global_load_lds the source permutation must
// equal the read layout exactly.)
// Structure: R14's per-thread work (2o x 2w x 4b, same math, same stat
// tree) in 64-thread blocks: block = 8o x 8w x 16b, grid dim3(16,30,8) =
// 3840 (~15-16 blocks/CU). 1-wave barrier has no partner convoy; per-channel
// vmcnt(0) drains are hidden by ~15 INDEPENDENT resident waves.
//  - weight LDS: 8 groups x 76 floats (608) + k8 plane 608..671.
//    staged as 10 full + 1 half-masked width-4 chunks (lane-linear).
//    wk b128 slot = (4oo+3og+4wg2+2ww) mod 8 -> all 8 slots hit 2x = free
//    (bg broadcasts). k8 b32 + ff reads: 2-way/broadcast = free.
//  - ff LDS: 576 floats, 3 width-16 chunks (3rd masked to 16 lanes).
//  - weight-sharing blocks (same x,y; 8 z) are 480 apart = 0 mod 8 -> same
//    XCD L2 (R6-proven requirement).
// Stats: same 960x32 f64 slots (4 os-blocks write disjoint o's), same 8
// values per lane, same og+4wg2+16bg butterfly -> BITWISE identical.
// Accumulation (c outer, kh, kw; mul-add, no FMA).
// NOTE (R4/R6 lessons): no VGPR cap, no pointer rotation, 2-deep only.
// ---------------------------------------------------------------------------
__global__ __launch_bounds__(64) void conv_kernel(
    const float* __restrict__ ff, const float* __restrict__ weight,
    const float* __restrict__ conv_bias, float* __restrict__ outf,
    double* __restrict__ part_sum, double* __restrict__ part_sumsq)
{
#pragma clang fp contract(off)
    const int tid = threadIdx.x;        // 0..63
    const int og  = tid & 3;            // 0..3
    const int wg2 = (tid >> 2) & 3;     // 0..3
    const int bg  = (tid >> 4) & 3;     // 0..3
    const int wt  = blockIdx.x & 3;     // 0..3
    const int os  = blockIdx.x >> 2;    // 0..3  (8-o slice: o = os*8 ..)
    const int h   = blockIdx.y;         // 0..29
    const int b0  = blockIdx.z * 16;    // 16 batches per block
    const int w0  = wt * 8 + wg2 * 2;
    const bool val = !(wt == 3 && wg2 == 3);
    const int ob  = os * 8;             // global o base

    __shared__ float wgl[2][672];       // 8x76 (608) + k8 plane 608..671
    __shared__ float ffs[2][576];       // [bb*36 + r*12 + cc]

    // ---- c-independent staging offsets (all in-bounds by construction) ----
    // weight chunks: padded pos m = q*64 + tid.
    //   m < 608 : group ol = m/76, in-group r = m%76.
    //             r < 64 -> DATA, layout w*8+k (MATCHES compute): w=r>>3, k=r&7.
    //             r 64..75 -> pad: src=0 (in-bounds, never read).
    //   608..671: k8 plane (ol*8 + w) -> weight k=8.
    int wq_off[11];
#pragma unroll
    for (int q = 0; q < 11; ++q) {
        int m = q * 64 + tid;           // q=10 masked to tid<32 at issue
        int src = 0;
        if (m < 608) {
            int ol = m / 76, r = m - ol * 76;
            if (r < 64) {
                int w = r >> 3, k = r & 7;
                int colc = wt * 8 + w; if (colc > 29) colc = 29;   // edge clamp
                src = (ob + ol) * WSTRIDE_O + (h * WO_ + colc) * 9 + k;
            }
        } else if (m < 672) {
            int idx = m - 608, ol = idx >> 3, w = idx & 7;
            int colc = wt * 8 + w; if (colc > 29) colc = 29;
            src = (ob + ol) * WSTRIDE_O + (h * WO_ + colc) * 9 + 8;
        }
        wq_off[q] = src;
    }
    // ff chunks: dword d = q*256 + tid*4; chunk 2 masked to tid<16.
    // each lane's 4 dwords stay within one 12-col row (d%12 in {0,4,8}).
    int f_off[3];
#pragma unroll
    for (int q = 0; q < 3; ++q) {
        int d = q * 256 + tid * 4;
        int dd = (d < 576) ? d : 0;
        int bb = dd / 36, rm = dd - bb * 36, r = rm / 12, cc0 = rm - r * 12;
        f_off[q] = (b0 + bb) * FFB_ + (h + r) * W_ + wt * 8 + cc0;  // 16B-aligned
    }

    float acc[2][2][4];                  // [oo][ww][j]
#pragma unroll
    for (int oo = 0; oo < 2; ++oo)
#pragma unroll
        for (int ww = 0; ww < 2; ++ww)
#pragma unroll
            for (int j = 0; j < 4; ++j) acc[oo][ww][j] = 0.f;

    auto stage = [&](int c, int buf) {
        const float* wsrc = weight + c * WSTRIDE_C;
#pragma unroll
        for (int q = 0; q < 10; ++q)
            gload_lds4(wsrc + wq_off[q], &wgl[buf][q * 64]);
        if (tid < 32)
            gload_lds4(wsrc + wq_off[10], &wgl[buf][640]);
#pragma unroll
        for (int q = 0; q < 3; ++q) {
            if (q < 2 || tid < 16) {
                int g = f_off[q] + c * FFC_;
                if (g > FFTOT_ - 4) g = FFTOT_ - 4;  // corner clamp (garbage slots only)
                gload_lds16(ff + g, &ffs[buf][q * 256]);
            }
        }
    };

    auto compute_c = [&](int buf) {
        float wk[2][2][9];
#pragma unroll
        for (int oo = 0; oo < 2; ++oo)
#pragma unroll
            for (int ww = 0; ww < 2; ++ww) {
                const int ol = oo * 4 + og, w = wg2 * 2 + ww;     // o-interleave
                const float* wp = &wgl[buf][ol * 76 + w * 8];     // 304B stride, 16B-aligned
                const float4 a = *reinterpret_cast<const float4*>(wp);
                const float4 b = *reinterpret_cast<const float4*>(wp + 4);
                wk[oo][ww][0] = a.x; wk[oo][ww][1] = a.y; wk[oo][ww][2] = a.z; wk[oo][ww][3] = a.w;
                wk[oo][ww][4] = b.x; wk[oo][ww][5] = b.y; wk[oo][ww][6] = b.z; wk[oo][ww][7] = b.w;
                wk[oo][ww][8] = wgl[buf][608 + ol * 8 + w];
            }
#pragma unroll
        for (int j = 0; j < 4; ++j) {
            const int bb = bg * 4 + j;
            float fr[3][4];
#pragma unroll
            for (int r = 0; r < 3; ++r) {
                const float2 u = *reinterpret_cast<const float2*>(&ffs[buf][bb * 36 + r * 12 + wg2 * 2]);
                const float2 v = *reinterpret_cast<const float2*>(&ffs[buf][bb * 36 + r * 12 + wg2 * 2 + 2]);
                fr[r][0] = u.x; fr[r][1] = u.y; fr[r][2] = v.x; fr[r][3] = v.y;
            }
#pragma unroll
            for (int oo = 0; oo < 2; ++oo)
#pragma unroll
                for (int ww = 0; ww < 2; ++ww) {
                    float a = acc[oo][ww][j];
#pragma unroll
                    for (int kh = 0; kh < 3; ++kh)
#pragma unroll
                        for (int kw = 0; kw < 3; ++kw) {
                            float prod = wk[oo][ww][kh * 3 + kw] * fr[kh][ww + kw];
                            a = a + prod;      // no FMA, (c,kh,kw) order
                        }
                    acc[oo][ww][j] = a;
                }
        }
    };

    stage(0, 0);
    __syncthreads();
    for (int cs = 0; cs < CI_; cs += 2) {
        if (cs + 1 < CI_) stage(cs + 1, 1);   // prefetch overlaps compute
        compute_c(0);
        __syncthreads();
        if (cs + 2 < CI_) stage(cs + 2, 0);
        compute_c(1);
        __syncthreads();
    }

    // epilogue: bias, park conv values, exact f64 per-slot per-channel stats
    double s1[2] = {0.0, 0.0}, s2[2] = {0.0, 0.0};
    if (val) {
#pragma unroll
        for (int oo = 0; oo < 2; ++oo) {
            const int o = ob + oo * 4 + og;
            const int pidx = o * P_ + h * WO_ + w0;
            const float2 bi = *reinterpret_cast<const float2*>(conv_bias + pidx);
#pragma unroll
            for (int j = 0; j < 4; ++j) {
                const int b = b0 + bg * 4 + j;
                const size_t n = (size_t)b * CP_ + (size_t)pidx;
                float v0 = acc[oo][0][j] + bi.x;     // f32, same as ref
                float v1 = acc[oo][1][j] + bi.y;
                *reinterpret_cast<float2*>(outf + 3 * N_ + n) = make_float2(v0, v1);
                double d0 = (double)v0, d1 = (double)v1;
                s1[oo] += d0; s2[oo] += d0 * d0;
                s1[oo] += d1; s2[oo] += d1 * d1;
            }
        }
    }
    // deterministic reduce over the 16 lanes (stride 4) sharing og
#pragma unroll
    for (int d = 4; d < 64; d <<= 1) {
#pragma unroll
        for (int oo = 0; oo < 2; ++oo) {
            s1[oo] += __shfl_xor(s1[oo], d);
            s2[oo] += __shfl_xor(s2[oo], d);
        }
    }
    if ((tid & 60) == 0) {               // wg2==0 && bg==0: tid 0..3
        int blk = (blockIdx.z * 30 + blockIdx.y) * 4 + wt;   // 0..959 (same slots)
#pragma unroll
        for (int oo = 0; oo < 2; ++oo) {
            const int o = ob + oo * 4 + og;
            part_sum  [blk * CO_ + o] = s1[oo];
            part_sumsq[blk * CO_ + o] = s2[oo];
        }
    }
}

// ---------------------------------------------------------------------------
// Kernel 2: BN finalize — deterministic f64 reduction of partials (960
// slots), then f32 mean / inv_std per channel. UNCHANGED.
// ---------------------------------------------------------------------------
__global__ __launch_bounds__(256) void bn_finalize(
    const double* __restrict__ part_sum, const double* __restrict__ part_sumsq,
    float* __restrict__ Mb)
{
#pragma clang fp contract(off)
    const int o = blockIdx.x;
    const int tid = threadIdx.x;
    double s1 = 0.0, s2 = 0.0;
    for (int i = tid; i < NBLK_CONV; i += 256) {
        s1 += part_sum[i * CO_ + o];
        s2 += part_sumsq[i * CO_ + o];
    }
    __shared__ double r1[256], r2[256];
    r1[tid] = s1; r2[tid] = s2;
    __syncthreads();
    for (int s = 128; s > 0; s >>= 1) {
        if (tid < s) { r1[tid] += r1[tid + s]; r2[tid] += r2[tid + s]; }
        __syncthreads();
    }
    if (tid == 0) {
        const double cnt = (double)(B_ * (size_t)P_);
        double mean = r1[0] / cnt;
        float meanf = (float)mean;
        double md = (double)meanf;
        double var = r2[0] / cnt - 2.0 * md * (r1[0] / cnt) + md * md;
        float varf = (float)var;
        float invf = 1.0f / sqrtf(varf + 1e-5f);
        Mb[o]       = meanf;
        Mb[CO_ + o] = invf;
    }
}

// ---------------------------------------------------------------------------
// Kernel 3: fused recurrent-bmm + LIF. R15 VERBATIM (best measured lif):
// 2 batches per barrier round, 4 spike tiles (16 KB), register prefetch,
// lgkmcnt(0)-only barrier; 1024 thr = 32 i x 32 p; XCD-grouped grid 512.
// ---------------------------------------------------------------------------
__global__ __launch_bounds__(1024) void lif_rec_kernel(
    float* __restrict__ outf, const float* __restrict__ local_rec,
    const float* __restrict__ tau_m, const float* __restrict__ tau_adp,
    const float* __restrict__ tau_a, const float* __restrict__ Mb,
    const float* __restrict__ gamma, const float* __restrict__ beta,
    const float* __restrict__ fb, const float* __restrict__ soma_t,
    const float* __restrict__ spk_t, const float* __restrict__ a_curr,
    const float* __restrict__ b_t)
{
#pragma clang fp contract(off)
    const int D    = blockIdx.x;
    const int pt8  = D & 7;
    const int rest = D >> 3;
    const int by   = rest & 15;
    const int ptq  = rest >> 4;          // 0..3
    const int pt   = ptq * 8 + pt8;      // 0..31
    if (pt >= 29) return;                // 29 p-tiles cover P_=900

    const int tid = threadIdx.x;
    const int pp  = tid & 31;
    const int i   = tid >> 5;            // channel 0..31
    const int p   = pt * 32 + pp;
    const bool pv = (p < P_);
    const int b0  = by * 8;

    float L[32];
    float meanf = 0.f, invf = 0.f, gm = 0.f, be = 0.f;
    float al = 0.f, rh = 0.f, et = 0.f;
    int rem = 0;
    if (pv) {
        const float4* lp = reinterpret_cast<const float4*>(local_rec + (size_t)p * (CO_ * CO_) + i * CO_);
#pragma unroll
        for (int q = 0; q < 8; ++q) {
            float4 v = lp[q];
            L[4 * q] = v.x; L[4 * q + 1] = v.y; L[4 * q + 2] = v.z; L[4 * q + 3] = v.w;
        }
        rem = i * P_ + p;
        meanf = Mb[i]; invf = Mb[CO_ + i];
        gm = gamma[i]; be = beta[i];
        // identical f32 ops to the original tau table: f32 divide then f32 exp
        al = expf(-0.5f / tau_m[rem]);
        rh = expf(-0.5f / tau_adp[rem]);
        et = expf(-0.5f / tau_a[rem]);
    }
    const float omr = 1.0f - rh;

    __shared__ float sp[4][CO_][32];     // 16 KB: two double-buffered tile PAIRS

    // prologue: operands for batches b0, b0+1
    size_t n = (size_t)b0 * CP_ + (size_t)rem;
    float sk0 = 0.f, cv0 = 0.f, bt0 = 0.f, ac0 = 0.f, fb0 = 0.f, so0 = 0.f;
    float sk1 = 0.f, cv1 = 0.f, bt1 = 0.f, ac1 = 0.f, fb1 = 0.f, so1 = 0.f;
    if (pv) {
        sk0 = spk_t[n];       cv0 = outf[3 * N_ + n];       bt0 = b_t[n];
        ac0 = a_curr[n];      fb0 = fb[n];                  so0 = soma_t[n];
        const size_t n1 = n + (size_t)CP_;
        sk1 = spk_t[n1];      cv1 = outf[3 * N_ + n1];      bt1 = b_t[n1];
        ac1 = a_curr[n1];     fb1 = fb[n1];                 so1 = soma_t[n1];
    }

#pragma unroll
    for (int r = 0; r < 4; ++r) {
        const int t0 = (r & 1) * 2;      // literal after unroll
        if (pv) {
            sp[t0][i][pp]     = sk0;
            sp[t0 + 1][i][pp] = sk1;
        }
        // prefetch operands for batches 2r+2, 2r+3 BEFORE the barrier
        float sk0n = 0.f, cv0n = 0.f, bt0n = 0.f, ac0n = 0.f, fb0n = 0.f, so0n = 0.f;
        float sk1n = 0.f, cv1n = 0.f, bt1n = 0.f, ac1n = 0.f, fb1n = 0.f, so1n = 0.f;
        if (r < 3 && pv) {
            const size_t n2 = n + (size_t)(2 * CP_);
            const size_t n3 = n + (size_t)(3 * CP_);
            sk0n = spk_t[n2];  cv0n = outf[3 * N_ + n2];  bt0n = b_t[n2];
            ac0n = a_curr[n2]; fb0n = fb[n2];             so0n = soma_t[n2];
            sk1n = spk_t[n3];  cv1n = outf[3 * N_ + n3];  bt1n = b_t[n3];
            ac1n = a_curr[n3]; fb1n = fb[n3];             so1n = soma_t[n3];
        }
        asm volatile("s_waitcnt lgkmcnt(0)\n\ts_barrier" ::: "memory");
        if (pv) {
            // ---- batch 2r ----
            {
                float rec = 0.f;
#pragma unroll
                for (int j = 0; j < CO_; ++j) {
                    float prod = L[j] * sp[t0][j][pp];
                    rec = rec + prod;
                }
                float t  = cv0 - meanf;
                float x  = t * invf;
                float xg = x * gm;
                float cx = xg + be;
                cx = cx + rec;
                float rb  = rh * bt0;
                float os  = omr * sk0;
                float bn  = rb + os;
                float tb = 1.8f * bn;
                float th = 0.1f + tb;
                float ea = et * ac0;
                float an = ea + fb0;
                float sg = 1.0f / (1.0f + expf(-an));
                float as = al * so0;
                float s5 = sg - 0.5f;
                float u1 = as + s5;
                float u2 = u1 + cx;
                float ts = th * sk0;
                float sn = u2 - ts;
                outf[n]          = sn;
                outf[N_ + n]     = ((sn - th) > 0.0f) ? 1.f : 0.f;
                outf[2 * N_ + n] = an;
                outf[3 * N_ + n] = bn;
            }
            // ---- batch 2r+1 ----
            {
                const size_t n1 = n + (size_t)CP_;
                float rec = 0.f;
#pragma unroll
                for (int j = 0; j < CO_; ++j) {
                    float prod = L[j] * sp[t0 + 1][j][pp];
                    rec = rec + prod;
                }
                float t  = cv1 - meanf;
                float x  = t * invf;
                float xg = x * gm;
                float cx = xg + be;
                cx = cx + rec;
                float rb  = rh * bt1;
                float os  = omr * sk1;
                float bn  = rb + os;
                float tb = 1.8f * bn;
                float th = 0.1f + tb;
                float ea = et * ac1;
                float an = ea + fb1;
                float sg = 1.0f / (1.0f + expf(-an));
                float as = al * so1;
                float s5 = sg - 0.5f;
                float u1 = as + s5;
                float u2 = u1 + cx;
                float ts = th * sk1;
                float sn = u2 - ts;
                outf[n1]          = sn;
                outf[N_ + n1]     = ((sn - th) > 0.0f) ? 1.f : 0.f;
                outf[2 * N_ + n1] = an;
                outf[3 * N_ + n1] = bn;
            }
        }
        sk0 = sk0n; cv0 = cv0n; bt0 = bt0n; ac0 = ac0n; fb0 = fb0n; so0 = so0n;
        sk1 = sk1n; cv1 = cv1n; bt1 = bt1n; ac1 = ac1n; fb1 = fb1n; so1 = so1n;
        n += (size_t)(2 * CP_);
    }
}

extern "C" void kernel_launch(void* const* d_in, const int* in_sizes, int n_in,
                              void* d_out, int out_size, void* d_ws, size_t ws_size,
                              hipStream_t stream)
{
    const float* ff        = (const float*)d_in[0];
    const float* fb        = (const float*)d_in[1];
    const float* soma_t    = (const float*)d_in[2];
    const float* spk_t     = (const float*)d_in[3];
    const float* a_curr    = (const float*)d_in[4];
    const float* b_t       = (const float*)d_in[5];
    const float* weight    = (const float*)d_in[6];
    const float* conv_bias = (const float*)d_in[7];
    const float* local_rec = (const float*)d_in[8];
    const float* gamma     = (const float*)d_in[9];
    const float* beta      = (const float*)d_in[10];
    const float* tau_m     = (const float*)d_in[11];
    const float* tau_adp   = (const float*)d_in[12];
    const float* tau_a     = (const float*)d_in[13];

    // ws: f64 partials then Mb (~0.5 MB total)
    double* part_sum = (double*)d_ws;                       // NBLK_CONV*CO_
    double* part_sq  = part_sum + (size_t)NBLK_CONV * CO_;  // NBLK_CONV*CO_
    float*  Mb       = (float*)(part_sq + (size_t)NBLK_CONV * CO_);  // 64

    float* outf = (float*)d_out;

    conv_kernel<<<dim3(16, 30, 8), 64, 0, stream>>>(
        ff, weight, conv_bias, outf, part_sum, part_sq);
    bn_finalize<<<dim3(CO_), 256, 0, stream>>>(part_sum, part_sq, Mb);
    lif_rec_kernel<<<dim3(512), 1024, 0, stream>>>(
        outf, local_rec, tau_m, tau_adp, tau_a, Mb, gamma, beta,
        fb, soma_t, spk_t, a_curr, b_t);
}